// Round 1
// baseline (1718.605 us; speedup 1.0000x reference)
//
#include <hip/hip_runtime.h>
#include <math.h>

#define NFEAT 128
#define NHID  64

__device__ __forceinline__ float wave_sum(float v) {
#pragma unroll
    for (int m = 1; m < 64; m <<= 1) v += __shfl_xor(v, m, 64);
    return v;
}

__device__ __forceinline__ float artanh_clip(float v) {
    const float lim = 0.99999988f;  // float(1 - 1e-7)
    v = fminf(fmaxf(v, -lim), lim);
    return 0.5f * logf((1.0f + v) / (1.0f - v));
}

// h0 = proj(expmap0(x)), x: [N,128]
__global__ __launch_bounds__(256) void k_expmap0_proj_x(
        const float* __restrict__ x, float* __restrict__ h, int n) {
    int wv = threadIdx.x >> 6, lane = threadIdx.x & 63;
    int node = blockIdx.x * 4 + wv;
    if (node >= n) return;
    const float* xr = x + (size_t)node * NFEAT;
    float v0 = xr[lane], v1 = xr[lane + 64];
    float ss = wave_sum(v0 * v0 + v1 * v1);
    float nrm = fmaxf(sqrtf(ss), 1e-15f);
    float f = tanhf(nrm) / nrm;        // expmap0 scale
    v0 *= f; v1 *= f;
    float ss2 = wave_sum(v0 * v0 + v1 * v1);
    float n2 = fmaxf(sqrtf(ss2), 1e-15f);
    if (n2 > 0.996f) { float s = 0.996f / n2; v0 *= s; v1 *= s; }
    float* hr = h + (size_t)node * NFEAT;
    hr[lane] = v0; hr[lane + 64] = v1;
}

// HypLinear + logmap0: ht = logmap0(proj(mobius_add(proj(mobius_matvec(W,h)), hyp_b)))
template <int DIN>
__global__ __launch_bounds__(256) void k_hyplinear(
        const float* __restrict__ h, const float* __restrict__ W,
        const float* __restrict__ b, float* __restrict__ ht, int n) {
    __shared__ float Wl[NHID * (DIN + 1)];
    __shared__ float hr[4][DIN];
    for (int idx = threadIdx.x; idx < NHID * DIN; idx += blockDim.x) {
        int r = idx / DIN, c = idx % DIN;
        Wl[r * (DIN + 1) + c] = W[idx];
    }
    int wv = threadIdx.x >> 6, lane = threadIdx.x & 63;
    int node = blockIdx.x * 4 + wv;
    float hv[DIN / 64];
    if (node < n) {
        const float* row = h + (size_t)node * DIN;
#pragma unroll
        for (int t = 0; t < DIN / 64; t++) {
            hv[t] = row[lane + t * 64];
            hr[wv][lane + t * 64] = hv[t];
        }
    }
    __syncthreads();
    if (node >= n) return;

    float ss = 0.f;
#pragma unroll
    for (int t = 0; t < DIN / 64; t++) ss += hv[t] * hv[t];
    ss = wave_sum(ss);
    float pn = fmaxf(sqrtf(ss), 1e-15f);

    // mp_j = sum_k h[k] * W[j,k], j = lane
    float mp = 0.f;
    const float* wrow = &Wl[lane * (DIN + 1)];
#pragma unroll 8
    for (int k = 0; k < DIN; k++) mp = fmaf(hr[wv][k], wrow[k], mp);

    float mpn = sqrtf(wave_sum(mp * mp));
    float targ = (mpn / pn) * artanh_clip(pn);
    float res = tanhf(targ) * mp / fmaxf(mpn, 1e-15f);
    if (mpn <= 1e-15f) res = 0.f;
    // proj
    float rn = fmaxf(sqrtf(wave_sum(res * res)), 1e-15f);
    if (rn > 0.996f) res *= 0.996f / rn;
    // hyp bias = proj(expmap0(b))
    float bv = b[lane];
    float bn = fmaxf(sqrtf(wave_sum(bv * bv)), 1e-15f);
    float hb = tanhf(bn) * bv / bn;
    float hbn = fmaxf(sqrtf(wave_sum(hb * hb)), 1e-15f);
    if (hbn > 0.996f) hb *= 0.996f / hbn;
    // mobius_add(res, hb)
    float x2 = wave_sum(res * res);
    float y2 = wave_sum(hb * hb);
    float xy = wave_sum(res * hb);
    float num = (1.f + 2.f * xy + y2) * res + (1.f - x2) * hb;
    float den = 1.f + 2.f * xy + x2 * y2;
    float m = num / fmaxf(den, 1e-15f);
    // proj
    float mn = fmaxf(sqrtf(wave_sum(m * m)), 1e-15f);
    if (mn > 0.996f) m *= 0.996f / mn;
    // logmap0
    float pn2 = fmaxf(sqrtf(wave_sum(m * m)), 1e-15f);
    float t = artanh_clip(pn2) * m / pn2;
    ht[(size_t)node * NHID + lane] = t;
}

// agg[dst] += adj * ht[src], one wave per edge
__global__ __launch_bounds__(256) void k_scatter(
        const float* __restrict__ ht, const int* __restrict__ src,
        const int* __restrict__ dst, const float* __restrict__ adj,
        float* __restrict__ agg, int e_cnt) {
    int e = blockIdx.x * 4 + (threadIdx.x >> 6);
    if (e >= e_cnt) return;
    int lane = threadIdx.x & 63;
    int s = src[e], d = dst[e];
    float a = adj[e];
    float v = a * ht[(size_t)s * NHID + lane];
    unsafeAtomicAdd(agg + (size_t)d * NHID + lane, v);
}

// h_next = proj(expmap0(relu(logmap0(proj(expmap0(agg))))))
__global__ __launch_bounds__(256) void k_hypact(
        const float* __restrict__ agg, float* __restrict__ hout, int n) {
    int node = blockIdx.x * 4 + (threadIdx.x >> 6);
    if (node >= n) return;
    int lane = threadIdx.x & 63;
    float u = agg[(size_t)node * NHID + lane];
    float un = fmaxf(sqrtf(wave_sum(u * u)), 1e-15f);
    float p = tanhf(un) * u / un;
    float pn = fmaxf(sqrtf(wave_sum(p * p)), 1e-15f);
    if (pn > 0.996f) p *= 0.996f / pn;
    float pn2 = fmaxf(sqrtf(wave_sum(p * p)), 1e-15f);
    float t = artanh_clip(pn2) * p / pn2;
    t = fmaxf(t, 0.f);
    float tn = fmaxf(sqrtf(wave_sum(t * t)), 1e-15f);
    float r = tanhf(tn) * t / tn;
    float rn = fmaxf(sqrtf(wave_sum(r * r)), 1e-15f);
    if (rn > 0.996f) r *= 0.996f / rn;
    hout[(size_t)node * NHID + lane] = r;
}

// head: t = logmap0(h); z = relu(t@W4.T+b4); out = log_softmax(z@W5.T+b5)
__global__ __launch_bounds__(256) void k_head(
        const float* __restrict__ h, const float* __restrict__ W4,
        const float* __restrict__ b4, const float* __restrict__ W5,
        const float* __restrict__ b5, float* __restrict__ out, int n) {
    __shared__ float W4l[32 * 65];
    __shared__ float W5l[16 * 33];
    __shared__ float tl[4][64];
    __shared__ float zl[4][33];
    for (int idx = threadIdx.x; idx < 32 * 64; idx += blockDim.x)
        W4l[(idx / 64) * 65 + (idx % 64)] = W4[idx];
    for (int idx = threadIdx.x; idx < 16 * 32; idx += blockDim.x)
        W5l[(idx / 32) * 33 + (idx % 32)] = W5[idx];
    int wv = threadIdx.x >> 6, lane = threadIdx.x & 63;
    int node = blockIdx.x * 4 + wv;
    if (node < n) {
        float hv = h[(size_t)node * NHID + lane];
        float hn = fmaxf(sqrtf(wave_sum(hv * hv)), 1e-15f);
        tl[wv][lane] = artanh_clip(hn) * hv / hn;
    }
    __syncthreads();
    if (lane < 32 && node < n) {
        float acc = b4[lane];
        const float* wr = &W4l[lane * 65];
#pragma unroll
        for (int j = 0; j < 64; j++) acc = fmaf(tl[wv][j], wr[j], acc);
        zl[wv][lane] = fmaxf(acc, 0.f);
    }
    __syncthreads();
    if (node >= n) return;
    float y = 0.f;
    if (lane < 16) {
        float acc = b5[lane];
        const float* wr = &W5l[lane * 33];
#pragma unroll
        for (int i = 0; i < 32; i++) acc = fmaf(zl[wv][i], wr[i], acc);
        y = acc;
    }
    // log_softmax across lanes 0..15 (xor masks stay inside the group)
    float mx = y;
#pragma unroll
    for (int mk = 1; mk < 16; mk <<= 1) mx = fmaxf(mx, __shfl_xor(mx, mk, 64));
    float ex = expf(y - mx);
    float sm = ex;
#pragma unroll
    for (int mk = 1; mk < 16; mk <<= 1) sm += __shfl_xor(sm, mk, 64);
    if (lane < 16) out[(size_t)node * 16 + lane] = y - mx - logf(sm);
}

extern "C" void kernel_launch(void* const* d_in, const int* in_sizes, int n_in,
                              void* d_out, int out_size, void* d_ws, size_t ws_size,
                              hipStream_t stream) {
    const float* x   = (const float*)d_in[0];
    const int*   src = (const int*)d_in[1];
    const int*   dst = (const int*)d_in[2];
    const float* adj = (const float*)d_in[3];
    const float* W1  = (const float*)d_in[4];  const float* b1 = (const float*)d_in[5];
    const float* W2  = (const float*)d_in[6];  const float* b2 = (const float*)d_in[7];
    const float* W3  = (const float*)d_in[8];  const float* b3 = (const float*)d_in[9];
    const float* W4  = (const float*)d_in[10]; const float* b4 = (const float*)d_in[11];
    const float* W5  = (const float*)d_in[12]; const float* b5 = (const float*)d_in[13];
    float* out = (float*)d_out;

    const int N = in_sizes[0] / NFEAT;
    const int E = in_sizes[1];

    // ws layout: A = [N,128] (h0; later reused: agg at offset 0, h_next at N*64)
    //            B = [N,64]  (ht)
    float* A = (float*)d_ws;
    float* B = A + (size_t)N * NFEAT;
    float* C = A;                       // agg   [N,64]
    float* D = A + (size_t)N * NHID;    // h_next[N,64]

    dim3 blk(256);
    int nodeBlocks = (N + 3) / 4;
    int edgeBlocks = (E + 3) / 4;
    size_t aggBytes = (size_t)N * NHID * sizeof(float);

    k_expmap0_proj_x<<<nodeBlocks, blk, 0, stream>>>(x, A, N);

    // layer 1 (din=128)
    k_hyplinear<128><<<nodeBlocks, blk, 0, stream>>>(A, W1, b1, B, N);
    hipMemsetAsync(C, 0, aggBytes, stream);
    k_scatter<<<edgeBlocks, blk, 0, stream>>>(B, src, dst, adj, C, E);
    k_hypact<<<nodeBlocks, blk, 0, stream>>>(C, D, N);

    // layer 2 (din=64)
    k_hyplinear<64><<<nodeBlocks, blk, 0, stream>>>(D, W2, b2, B, N);
    hipMemsetAsync(C, 0, aggBytes, stream);
    k_scatter<<<edgeBlocks, blk, 0, stream>>>(B, src, dst, adj, C, E);
    k_hypact<<<nodeBlocks, blk, 0, stream>>>(C, D, N);

    // layer 3 (din=64)
    k_hyplinear<64><<<nodeBlocks, blk, 0, stream>>>(D, W3, b3, B, N);
    hipMemsetAsync(C, 0, aggBytes, stream);
    k_scatter<<<edgeBlocks, blk, 0, stream>>>(B, src, dst, adj, C, E);
    k_hypact<<<nodeBlocks, blk, 0, stream>>>(C, D, N);

    // head
    k_head<<<nodeBlocks, blk, 0, stream>>>(D, W4, b4, W5, b5, out, N);
}

// Round 2
// 1018.506 us; speedup vs baseline: 1.6874x; 1.6874x over previous
//
#include <hip/hip_runtime.h>
#include <math.h>

#define NFEAT 128
#define NHID  64
#define SCAN_B 1024   // elements per scan1 block (256 thr x 4)

__device__ __forceinline__ float wave_sum(float v) {
#pragma unroll
    for (int m = 1; m < 64; m <<= 1) v += __shfl_xor(v, m, 64);
    return v;
}

__device__ __forceinline__ float artanh_clip(float v) {
    const float lim = 0.99999988f;  // float(1 - 1e-7)
    v = fminf(fmaxf(v, -lim), lim);
    return 0.5f * logf((1.0f + v) / (1.0f - v));
}

// Shared tail of HypLinear: mp (matvec result, per-lane), pn (input ball norm)
// -> tangent vector t (logmap0 of biased, projected result)
__device__ __forceinline__ float hyp_tail(float mp, float pn,
                                          const float* __restrict__ b, int lane) {
    float mpn = sqrtf(wave_sum(mp * mp));
    float targ = (mpn / pn) * artanh_clip(pn);
    float res = tanhf(targ) * mp / fmaxf(mpn, 1e-15f);
    if (mpn <= 1e-15f) res = 0.f;
    float rn = fmaxf(sqrtf(wave_sum(res * res)), 1e-15f);
    if (rn > 0.996f) res *= 0.996f / rn;
    // hyp bias = proj(expmap0(b))
    float bv = b[lane];
    float bn = fmaxf(sqrtf(wave_sum(bv * bv)), 1e-15f);
    float hb = tanhf(bn) * bv / bn;
    float hbn = fmaxf(sqrtf(wave_sum(hb * hb)), 1e-15f);
    if (hbn > 0.996f) hb *= 0.996f / hbn;
    // mobius_add(res, hb)
    float x2 = wave_sum(res * res);
    float y2 = wave_sum(hb * hb);
    float xy = wave_sum(res * hb);
    float num = (1.f + 2.f * xy + y2) * res + (1.f - x2) * hb;
    float den = 1.f + 2.f * xy + x2 * y2;
    float m = num / fmaxf(den, 1e-15f);
    float mn = fmaxf(sqrtf(wave_sum(m * m)), 1e-15f);
    if (mn > 0.996f) m *= 0.996f / mn;
    float pn2 = fmaxf(sqrtf(wave_sum(m * m)), 1e-15f);
    return artanh_clip(pn2) * m / pn2;
}

// ---- CSR build --------------------------------------------------------------

__global__ __launch_bounds__(256) void k_hist(const int* __restrict__ dst,
                                              int* __restrict__ cnt, int e) {
    int i = blockIdx.x * 256 + threadIdx.x;
    if (i < e) atomicAdd(&cnt[dst[i]], 1);
}

__global__ __launch_bounds__(256) void k_scan1(const int* __restrict__ cnt,
        int* __restrict__ off, int* __restrict__ bsums, int n) {
    __shared__ int s[256];
    int tid = threadIdx.x;
    int base = blockIdx.x * SCAN_B + tid * 4;
    int c0 = 0, c1 = 0, c2 = 0, c3 = 0;
    if (base + 0 < n) c0 = cnt[base + 0];
    if (base + 1 < n) c1 = cnt[base + 1];
    if (base + 2 < n) c2 = cnt[base + 2];
    if (base + 3 < n) c3 = cnt[base + 3];
    int tsum = c0 + c1 + c2 + c3;
    s[tid] = tsum; __syncthreads();
    for (int o = 1; o < 256; o <<= 1) {
        int v = (tid >= o) ? s[tid - o] : 0;
        __syncthreads();
        s[tid] += v;
        __syncthreads();
    }
    int excl = s[tid] - tsum;
    if (base + 0 < n) off[base + 0] = excl;
    if (base + 1 < n) off[base + 1] = excl + c0;
    if (base + 2 < n) off[base + 2] = excl + c0 + c1;
    if (base + 3 < n) off[base + 3] = excl + c0 + c1 + c2;
    if (tid == 255) bsums[blockIdx.x] = s[255];
}

// single block: exclusive-scan bsums[0..nb-1] in place (nb <= 1024); also
// writes off[ntot] = grand total (== E)
__global__ __launch_bounds__(256) void k_scan2(int* __restrict__ bsums, int nb,
                                               int* __restrict__ off, int ntot) {
    __shared__ int s[256];
    int tid = threadIdx.x;
    int base = tid * 4;
    int c0 = 0, c1 = 0, c2 = 0, c3 = 0;
    if (base + 0 < nb) c0 = bsums[base + 0];
    if (base + 1 < nb) c1 = bsums[base + 1];
    if (base + 2 < nb) c2 = bsums[base + 2];
    if (base + 3 < nb) c3 = bsums[base + 3];
    int tsum = c0 + c1 + c2 + c3;
    s[tid] = tsum; __syncthreads();
    for (int o = 1; o < 256; o <<= 1) {
        int v = (tid >= o) ? s[tid - o] : 0;
        __syncthreads();
        s[tid] += v;
        __syncthreads();
    }
    int excl = s[tid] - tsum;
    if (base + 0 < nb) bsums[base + 0] = excl;
    if (base + 1 < nb) bsums[base + 1] = excl + c0;
    if (base + 2 < nb) bsums[base + 2] = excl + c0 + c1;
    if (base + 3 < nb) bsums[base + 3] = excl + c0 + c1 + c2;
    if (tid == 255) off[ntot] = s[255];
}

// off[i] += bsums[block]; ptr[i] = off[i]  (ptr = running fill cursor)
__global__ __launch_bounds__(256) void k_scan3(int* __restrict__ off,
        int* __restrict__ ptr, const int* __restrict__ bsums, int n) {
    int i = blockIdx.x * 256 + threadIdx.x;
    if (i < n) {
        int v = off[i] + bsums[i >> 10];
        off[i] = v;
        ptr[i] = v;
    }
}

__global__ __launch_bounds__(256) void k_permute(const int* __restrict__ src,
        const int* __restrict__ dst, const float* __restrict__ adj,
        int* __restrict__ ptr, int* __restrict__ sp, float* __restrict__ ap,
        int e) {
    int i = blockIdx.x * 256 + threadIdx.x;
    if (i < e) {
        int d = dst[i];
        int pos = atomicAdd(&ptr[d], 1);
        sp[pos] = src[i];
        ap[pos] = adj[i];
    }
}

// ---- layer kernels ----------------------------------------------------------

// layer 1: fused h = proj(expmap0(x)) then HypLinear(W1)+logmap0 -> ht
__global__ __launch_bounds__(256) void k_hyplin1(
        const float* __restrict__ x, const float* __restrict__ W,
        const float* __restrict__ b, float* __restrict__ ht, int n) {
    __shared__ float Wl[NHID * (NFEAT + 1)];
    __shared__ float hr[4][NFEAT];
    for (int idx = threadIdx.x; idx < NHID * NFEAT; idx += 256)
        Wl[(idx >> 7) * (NFEAT + 1) + (idx & 127)] = W[idx];
    int wv = threadIdx.x >> 6, lane = threadIdx.x & 63;
    int node = blockIdx.x * 4 + wv;
    float v0 = 0.f, v1 = 0.f;
    if (node < n) {
        const float* xr = x + (size_t)node * NFEAT;
        v0 = xr[lane]; v1 = xr[lane + 64];
        float ss = wave_sum(v0 * v0 + v1 * v1);
        float nrm = fmaxf(sqrtf(ss), 1e-15f);
        float f = tanhf(nrm) / nrm;
        v0 *= f; v1 *= f;
        float n2 = fmaxf(sqrtf(wave_sum(v0 * v0 + v1 * v1)), 1e-15f);
        if (n2 > 0.996f) { float s2 = 0.996f / n2; v0 *= s2; v1 *= s2; }
        hr[wv][lane] = v0; hr[wv][lane + 64] = v1;
    }
    __syncthreads();
    if (node >= n) return;
    float pn = fmaxf(sqrtf(wave_sum(v0 * v0 + v1 * v1)), 1e-15f);
    float mp = 0.f;
    const float* wrow = &Wl[lane * (NFEAT + 1)];
#pragma unroll 8
    for (int k = 0; k < NFEAT; k++) mp = fmaf(hr[wv][k], wrow[k], mp);
    ht[(size_t)node * NHID + lane] = hyp_tail(mp, pn, b, lane);
}

// layers 2/3: HypLinear(W)+logmap0 on a ball point h[N,64] -> ht
__global__ __launch_bounds__(256) void k_hyplin64(
        const float* __restrict__ h, const float* __restrict__ W,
        const float* __restrict__ b, float* __restrict__ ht, int n) {
    __shared__ float Wl[NHID * (NHID + 1)];
    __shared__ float hr[4][NHID];
    for (int idx = threadIdx.x; idx < NHID * NHID; idx += 256)
        Wl[(idx >> 6) * (NHID + 1) + (idx & 63)] = W[idx];
    int wv = threadIdx.x >> 6, lane = threadIdx.x & 63;
    int node = blockIdx.x * 4 + wv;
    float hv = 0.f;
    if (node < n) {
        hv = h[(size_t)node * NHID + lane];
        hr[wv][lane] = hv;
    }
    __syncthreads();
    if (node >= n) return;
    float pn = fmaxf(sqrtf(wave_sum(hv * hv)), 1e-15f);
    float mp = 0.f;
    const float* wrow = &Wl[lane * (NHID + 1)];
#pragma unroll 8
    for (int k = 0; k < NHID; k++) mp = fmaf(hr[wv][k], wrow[k], mp);
    ht[(size_t)node * NHID + lane] = hyp_tail(mp, pn, b, lane);
}

// CSR aggregation (no atomics) + HypAct fused:
// hout = proj(expmap0(relu(logmap0(proj(expmap0(sum adj*ht[src]))))))
__global__ __launch_bounds__(256) void k_agg_act(
        const float* __restrict__ ht, const int* __restrict__ off,
        const int* __restrict__ sp, const float* __restrict__ ap,
        float* __restrict__ hout, int n) {
    int wv = threadIdx.x >> 6, lane = threadIdx.x & 63;
    int node = blockIdx.x * 4 + wv;
    if (node >= n) return;
    int beg = off[node], end = off[node + 1];
    float acc = 0.f;
    int e = beg;
    for (; e + 1 < end; e += 2) {
        int s0 = sp[e], s1 = sp[e + 1];
        float a0 = ap[e], a1 = ap[e + 1];
        float x0 = ht[(size_t)s0 * NHID + lane];
        float x1 = ht[(size_t)s1 * NHID + lane];
        acc = fmaf(a0, x0, acc);
        acc = fmaf(a1, x1, acc);
    }
    if (e < end) acc = fmaf(ap[e], ht[(size_t)sp[e] * NHID + lane], acc);
    // HypAct
    float un = fmaxf(sqrtf(wave_sum(acc * acc)), 1e-15f);
    float p = tanhf(un) * acc / un;
    float pn = fmaxf(sqrtf(wave_sum(p * p)), 1e-15f);
    if (pn > 0.996f) p *= 0.996f / pn;
    float pn2 = fmaxf(sqrtf(wave_sum(p * p)), 1e-15f);
    float t = artanh_clip(pn2) * p / pn2;
    t = fmaxf(t, 0.f);
    float tn = fmaxf(sqrtf(wave_sum(t * t)), 1e-15f);
    float r = tanhf(tn) * t / tn;
    float rn = fmaxf(sqrtf(wave_sum(r * r)), 1e-15f);
    if (rn > 0.996f) r *= 0.996f / rn;
    hout[(size_t)node * NHID + lane] = r;
}

// head: t = logmap0(h); z = relu(t@W4.T+b4); out = log_softmax(z@W5.T+b5)
__global__ __launch_bounds__(256) void k_head(
        const float* __restrict__ h, const float* __restrict__ W4,
        const float* __restrict__ b4, const float* __restrict__ W5,
        const float* __restrict__ b5, float* __restrict__ out, int n) {
    __shared__ float W4l[32 * 65];
    __shared__ float W5l[16 * 33];
    __shared__ float tl[4][64];
    __shared__ float zl[4][33];
    for (int idx = threadIdx.x; idx < 32 * 64; idx += 256)
        W4l[(idx / 64) * 65 + (idx % 64)] = W4[idx];
    for (int idx = threadIdx.x; idx < 16 * 32; idx += 256)
        W5l[(idx / 32) * 33 + (idx % 32)] = W5[idx];
    int wv = threadIdx.x >> 6, lane = threadIdx.x & 63;
    int node = blockIdx.x * 4 + wv;
    if (node < n) {
        float hv = h[(size_t)node * NHID + lane];
        float hn = fmaxf(sqrtf(wave_sum(hv * hv)), 1e-15f);
        tl[wv][lane] = artanh_clip(hn) * hv / hn;
    }
    __syncthreads();
    if (lane < 32 && node < n) {
        float acc = b4[lane];
        const float* wr = &W4l[lane * 65];
#pragma unroll
        for (int j = 0; j < 64; j++) acc = fmaf(tl[wv][j], wr[j], acc);
        zl[wv][lane] = fmaxf(acc, 0.f);
    }
    __syncthreads();
    if (node >= n) return;
    float y = 0.f;
    if (lane < 16) {
        float acc = b5[lane];
        const float* wr = &W5l[lane * 33];
#pragma unroll
        for (int i = 0; i < 32; i++) acc = fmaf(zl[wv][i], wr[i], acc);
        y = acc;
    }
    float mx = y;
#pragma unroll
    for (int mk = 1; mk < 16; mk <<= 1) mx = fmaxf(mx, __shfl_xor(mx, mk, 64));
    float ex = expf(y - mx);
    float sm = ex;
#pragma unroll
    for (int mk = 1; mk < 16; mk <<= 1) sm += __shfl_xor(sm, mk, 64);
    if (lane < 16) out[(size_t)node * 16 + lane] = y - mx - logf(sm);
}

extern "C" void kernel_launch(void* const* d_in, const int* in_sizes, int n_in,
                              void* d_out, int out_size, void* d_ws, size_t ws_size,
                              hipStream_t stream) {
    const float* x   = (const float*)d_in[0];
    const int*   src = (const int*)d_in[1];
    const int*   dst = (const int*)d_in[2];
    const float* adj = (const float*)d_in[3];
    const float* W1  = (const float*)d_in[4];  const float* b1 = (const float*)d_in[5];
    const float* W2  = (const float*)d_in[6];  const float* b2 = (const float*)d_in[7];
    const float* W3  = (const float*)d_in[8];  const float* b3 = (const float*)d_in[9];
    const float* W4  = (const float*)d_in[10]; const float* b4 = (const float*)d_in[11];
    const float* W5  = (const float*)d_in[12]; const float* b5 = (const float*)d_in[13];
    float* out = (float*)d_out;

    const int N = in_sizes[0] / NFEAT;
    const int E = in_sizes[1];

    // ws layout (ints first, then floats)
    int* off   = (int*)d_ws;           // N+1
    int* cnt   = off + (N + 1);        // N   (histogram, then fill cursor)
    int* bsums = cnt + N;              // 1024
    int* sp    = bsums + 1024;         // E   (src permuted by dst)
    float* ap  = (float*)(sp + E);     // E   (adj permuted by dst)
    float* B   = ap + E;               // ht     [N,64]
    float* D   = B + (size_t)N * NHID; // h_next [N,64]

    dim3 blk(256);
    int nodeBlocks = (N + 3) / 4;
    int edgeThBlocks = (E + 255) / 256;
    int nb = (N + SCAN_B - 1) / SCAN_B;

    // ---- CSR build (once, reused by all 3 layers) ----
    hipMemsetAsync(cnt, 0, (size_t)N * sizeof(int), stream);
    k_hist<<<edgeThBlocks, blk, 0, stream>>>(dst, cnt, E);
    k_scan1<<<nb, blk, 0, stream>>>(cnt, off, bsums, N);
    k_scan2<<<1, blk, 0, stream>>>(bsums, nb, off, N);
    k_scan3<<<(N + 255) / 256, blk, 0, stream>>>(off, cnt, bsums, N);
    k_permute<<<edgeThBlocks, blk, 0, stream>>>(src, dst, adj, cnt, sp, ap, E);

    // ---- layer 1 (din=128, fused expmap0(x)+proj) ----
    k_hyplin1<<<nodeBlocks, blk, 0, stream>>>(x, W1, b1, B, N);
    k_agg_act<<<nodeBlocks, blk, 0, stream>>>(B, off, sp, ap, D, N);

    // ---- layer 2 ----
    k_hyplin64<<<nodeBlocks, blk, 0, stream>>>(D, W2, b2, B, N);
    k_agg_act<<<nodeBlocks, blk, 0, stream>>>(B, off, sp, ap, D, N);

    // ---- layer 3 ----
    k_hyplin64<<<nodeBlocks, blk, 0, stream>>>(D, W3, b3, B, N);
    k_agg_act<<<nodeBlocks, blk, 0, stream>>>(B, off, sp, ap, D, N);

    // ---- head ----
    k_head<<<nodeBlocks, blk, 0, stream>>>(D, W4, b4, W5, b5, out, N);
}

// Round 3
// 728.341 us; speedup vs baseline: 2.3596x; 1.3984x over previous
//
#include <hip/hip_runtime.h>
#include <math.h>

#define NFEAT 128
#define NHID  64
#define SCAN_B 1024   // elements per scan1 block (256 thr x 4)

__device__ __forceinline__ float wave_sum(float v) {
#pragma unroll
    for (int m = 1; m < 64; m <<= 1) v += __shfl_xor(v, m, 64);
    return v;
}

__device__ __forceinline__ float fast_tanh(float x) {
    // tanh(x) = 1 - 2/(exp(2x)+1); exact at 0, handles overflow (-> 1)
    float e = __expf(2.f * x);
    return 1.f - 2.f / (e + 1.f);
}

__device__ __forceinline__ float artanh_clip(float v) {
    const float lim = 0.99999988f;  // float(1 - 1e-7)
    v = fminf(fmaxf(v, -lim), lim);
    return 0.5f * __logf((1.f + v) / (1.f - v));
}

// HypLinear tail with analytic norms. mp: matvec result (lane j), pn: input
// ball norm (uniform). hb/hbn: precomputed hyperbolic bias and its norm.
__device__ __forceinline__ float hyp_tail_fast(float mp, float pn,
        const float* __restrict__ hb, float hbn, int lane) {
    float mpn = sqrtf(wave_sum(mp * mp));                 // reduction 1
    float targ = (mpn / pn) * artanh_clip(pn);
    float th = fast_tanh(targ);                            // = ||res|| exactly
    float res = th * mp / fmaxf(mpn, 1e-15f);
    float rn = th;
    if (mpn <= 1e-15f) { res = 0.f; rn = 0.f; }
    if (rn > 0.996f) { res *= 0.996f / rn; rn = 0.996f; }  // proj, analytic
    float m = res, mn = rn;
    if (hbn > 1e-15f) {                                    // general bias path
        float hbv = hb[lane];
        float x2 = rn * rn, y2 = hbn * hbn;
        float xy = wave_sum(res * hbv);                    // reduction 2
        float num = (1.f + 2.f * xy + y2) * res + (1.f - x2) * hbv;
        float den = 1.f + 2.f * xy + x2 * y2;
        m = num / fmaxf(den, 1e-15f);
        mn = sqrtf(wave_sum(m * m));                       // reduction 3
        if (mn > 0.996f) { m *= 0.996f / mn; mn = 0.996f; }
    }
    float pn2 = fmaxf(mn, 1e-15f);
    return artanh_clip(pn2) / pn2 * m;                     // logmap0
}

// ---- CSR build --------------------------------------------------------------

__global__ __launch_bounds__(256) void k_hist(const int* __restrict__ dst,
                                              int* __restrict__ cnt, int e) {
    int i = blockIdx.x * 256 + threadIdx.x;
    if (i < e) atomicAdd(&cnt[dst[i]], 1);
}

__global__ __launch_bounds__(256) void k_scan1(const int* __restrict__ cnt,
        int* __restrict__ off, int* __restrict__ bsums, int n) {
    __shared__ int s[256];
    int tid = threadIdx.x;
    int base = blockIdx.x * SCAN_B + tid * 4;
    int c0 = 0, c1 = 0, c2 = 0, c3 = 0;
    if (base + 0 < n) c0 = cnt[base + 0];
    if (base + 1 < n) c1 = cnt[base + 1];
    if (base + 2 < n) c2 = cnt[base + 2];
    if (base + 3 < n) c3 = cnt[base + 3];
    int tsum = c0 + c1 + c2 + c3;
    s[tid] = tsum; __syncthreads();
    for (int o = 1; o < 256; o <<= 1) {
        int v = (tid >= o) ? s[tid - o] : 0;
        __syncthreads();
        s[tid] += v;
        __syncthreads();
    }
    int excl = s[tid] - tsum;
    if (base + 0 < n) off[base + 0] = excl;
    if (base + 1 < n) off[base + 1] = excl + c0;
    if (base + 2 < n) off[base + 2] = excl + c0 + c1;
    if (base + 3 < n) off[base + 3] = excl + c0 + c1 + c2;
    if (tid == 255) bsums[blockIdx.x] = s[255];
}

__global__ __launch_bounds__(256) void k_scan2(int* __restrict__ bsums, int nb,
                                               int* __restrict__ off, int ntot) {
    __shared__ int s[256];
    int tid = threadIdx.x;
    int base = tid * 4;
    int c0 = 0, c1 = 0, c2 = 0, c3 = 0;
    if (base + 0 < nb) c0 = bsums[base + 0];
    if (base + 1 < nb) c1 = bsums[base + 1];
    if (base + 2 < nb) c2 = bsums[base + 2];
    if (base + 3 < nb) c3 = bsums[base + 3];
    int tsum = c0 + c1 + c2 + c3;
    s[tid] = tsum; __syncthreads();
    for (int o = 1; o < 256; o <<= 1) {
        int v = (tid >= o) ? s[tid - o] : 0;
        __syncthreads();
        s[tid] += v;
        __syncthreads();
    }
    int excl = s[tid] - tsum;
    if (base + 0 < nb) bsums[base + 0] = excl;
    if (base + 1 < nb) bsums[base + 1] = excl + c0;
    if (base + 2 < nb) bsums[base + 2] = excl + c0 + c1;
    if (base + 3 < nb) bsums[base + 3] = excl + c0 + c1 + c2;
    if (tid == 255) off[ntot] = s[255];
}

__global__ __launch_bounds__(256) void k_scan3(int* __restrict__ off,
        int* __restrict__ ptr, const int* __restrict__ bsums, int n) {
    int i = blockIdx.x * 256 + threadIdx.x;
    if (i < n) {
        int v = off[i] + bsums[i >> 10];
        off[i] = v;
        ptr[i] = v;
    }
}

__global__ __launch_bounds__(256) void k_permute(const int* __restrict__ src,
        const int* __restrict__ dst, const float* __restrict__ adj,
        int* __restrict__ ptr, float2* __restrict__ pe, int e) {
    int i = blockIdx.x * 256 + threadIdx.x;
    if (i < e) {
        int d = dst[i];
        int pos = atomicAdd(&ptr[d], 1);
        pe[pos] = make_float2(__int_as_float(src[i]), adj[i]);
    }
}

// hyperbolic bias per layer: hbs[l*64+j] = proj(expmap0(b_l))_j, hbns[l] = norm
__global__ __launch_bounds__(192) void k_bias(const float* __restrict__ b1,
        const float* __restrict__ b2, const float* __restrict__ b3,
        float* __restrict__ hbs, float* __restrict__ hbns) {
    int wv = threadIdx.x >> 6, lane = threadIdx.x & 63;
    const float* b = (wv == 0) ? b1 : (wv == 1) ? b2 : b3;
    float bv = b[lane];
    float bn = fmaxf(sqrtf(wave_sum(bv * bv)), 1e-15f);
    float th = fast_tanh(bn);
    float f = th / bn;
    float hn = th;
    if (th > 0.996f) { f = 0.996f / bn; hn = 0.996f; }
    hbs[wv * 64 + lane] = bv * f;
    if (lane == 0) hbns[wv] = hn;
}

// ---- layer kernels ----------------------------------------------------------

// layer 1: persistent waves, W row in 128 VGPRs, fused expmap0(x)+proj
__global__ __launch_bounds__(256, 2) void k_hyplin1(
        const float* __restrict__ x, const float* __restrict__ W,
        const float* __restrict__ hb, const float* __restrict__ hbn_p,
        float* __restrict__ ht, int n) {
    __shared__ __align__(16) float hs[4][NFEAT];
    int wv = threadIdx.x >> 6, lane = threadIdx.x & 63;
    float w[NFEAT];
    const float* wr = W + (size_t)lane * NFEAT;
#pragma unroll
    for (int kk = 0; kk < NFEAT / 4; kk++) {
        float4 t4 = *(const float4*)(wr + 4 * kk);
        w[4 * kk + 0] = t4.x; w[4 * kk + 1] = t4.y;
        w[4 * kk + 2] = t4.z; w[4 * kk + 3] = t4.w;
    }
    float hbn = hbn_p[0];
    int wid = blockIdx.x * 4 + wv;
    int nw = gridDim.x * 4;
    for (int node = wid; node < n; node += nw) {
        int nu = __builtin_amdgcn_readfirstlane(node);
        const float* xr = x + (size_t)nu * NFEAT;
        float v0 = xr[lane], v1 = xr[lane + 64];
        float nrm = fmaxf(sqrtf(wave_sum(v0 * v0 + v1 * v1)), 1e-15f);
        float th = fast_tanh(nrm);
        float f = th / nrm;
        float pn = fmaxf(th, 1e-15f);
        if (th > 0.996f) { f = 0.996f / nrm; pn = 0.996f; }
        v0 *= f; v1 *= f;
        hs[wv][lane] = v0; hs[wv][lane + 64] = v1;
        float mp = 0.f;
#pragma unroll
        for (int kk = 0; kk < NFEAT / 4; kk++) {
            float4 h4 = *(const float4*)&hs[wv][4 * kk];   // LDS broadcast
            mp = fmaf(h4.x, w[4 * kk + 0], mp);
            mp = fmaf(h4.y, w[4 * kk + 1], mp);
            mp = fmaf(h4.z, w[4 * kk + 2], mp);
            mp = fmaf(h4.w, w[4 * kk + 3], mp);
        }
        ht[(size_t)nu * NHID + lane] = hyp_tail_fast(mp, pn, hb, hbn, lane);
    }
}

// layers 2/3: same, DIN=64, input ball norm from aux array (no reduction)
__global__ __launch_bounds__(256, 3) void k_hyplin64(
        const float* __restrict__ h, const float* __restrict__ nrm_in,
        const float* __restrict__ W, const float* __restrict__ hb,
        const float* __restrict__ hbn_p, float* __restrict__ ht, int n) {
    __shared__ __align__(16) float hs[4][NHID];
    int wv = threadIdx.x >> 6, lane = threadIdx.x & 63;
    float w[NHID];
    const float* wr = W + (size_t)lane * NHID;
#pragma unroll
    for (int kk = 0; kk < NHID / 4; kk++) {
        float4 t4 = *(const float4*)(wr + 4 * kk);
        w[4 * kk + 0] = t4.x; w[4 * kk + 1] = t4.y;
        w[4 * kk + 2] = t4.z; w[4 * kk + 3] = t4.w;
    }
    float hbn = hbn_p[0];
    int wid = blockIdx.x * 4 + wv;
    int nw = gridDim.x * 4;
    for (int node = wid; node < n; node += nw) {
        int nu = __builtin_amdgcn_readfirstlane(node);
        float hv = h[(size_t)nu * NHID + lane];
        hs[wv][lane] = hv;
        float pn = nrm_in[nu];
        float mp = 0.f;
#pragma unroll
        for (int kk = 0; kk < NHID / 4; kk++) {
            float4 h4 = *(const float4*)&hs[wv][4 * kk];
            mp = fmaf(h4.x, w[4 * kk + 0], mp);
            mp = fmaf(h4.y, w[4 * kk + 1], mp);
            mp = fmaf(h4.z, w[4 * kk + 2], mp);
            mp = fmaf(h4.w, w[4 * kk + 3], mp);
        }
        ht[(size_t)nu * NHID + lane] = hyp_tail_fast(mp, pn, hb, hbn, lane);
    }
}

// CSR aggregation + HypAct, analytic norms; writes ball point + its norm
__global__ __launch_bounds__(256) void k_agg_act(
        const float* __restrict__ ht, const int* __restrict__ off,
        const float2* __restrict__ pe, float* __restrict__ hout,
        float* __restrict__ nrm_out, int n) {
    int wv = threadIdx.x >> 6, lane = threadIdx.x & 63;
    int node = blockIdx.x * 4 + wv;
    if (node >= n) return;
    node = __builtin_amdgcn_readfirstlane(node);
    int beg = off[node], end = off[node + 1];
    float acc = 0.f;
    int e = beg;
    for (; e + 1 < end; e += 2) {
        float2 p0 = pe[e], p1 = pe[e + 1];
        int s0 = __float_as_int(p0.x), s1 = __float_as_int(p1.x);
        acc = fmaf(p0.y, ht[(size_t)s0 * NHID + lane], acc);
        acc = fmaf(p1.y, ht[(size_t)s1 * NHID + lane], acc);
    }
    if (e < end) {
        float2 p0 = pe[e];
        acc = fmaf(p0.y, ht[(size_t)__float_as_int(p0.x) * NHID + lane], acc);
    }
    float un = fmaxf(sqrtf(wave_sum(acc * acc)), 1e-15f);   // reduction 1
    float thu = fast_tanh(un);
    float p = thu / un * acc;
    float pn = fmaxf(thu, 1e-15f);
    if (thu > 0.996f) { p *= 0.996f / thu; pn = 0.996f; }
    float t = artanh_clip(pn) / pn * p;
    t = fmaxf(t, 0.f);                                      // relu
    float tn = fmaxf(sqrtf(wave_sum(t * t)), 1e-15f);       // reduction 2
    float tht = fast_tanh(tn);
    float r = tht / tn * t;
    float rn = fmaxf(tht, 1e-15f);
    if (tht > 0.996f) { r *= 0.996f / tht; rn = 0.996f; }
    hout[(size_t)node * NHID + lane] = r;
    if (lane == 0) nrm_out[node] = rn;
}

// head: t = logmap0(h) (norm from aux); z = relu(t@W4.T+b4); log_softmax(z@W5.T+b5)
__global__ __launch_bounds__(256) void k_head(
        const float* __restrict__ h, const float* __restrict__ nrm_in,
        const float* __restrict__ W4, const float* __restrict__ b4,
        const float* __restrict__ W5, const float* __restrict__ b5,
        float* __restrict__ out, int n) {
    __shared__ float W4l[32 * 65];
    __shared__ float W5l[16 * 33];
    __shared__ float tl[4][64];
    __shared__ float zl[4][33];
    for (int idx = threadIdx.x; idx < 32 * 64; idx += 256)
        W4l[(idx / 64) * 65 + (idx % 64)] = W4[idx];
    for (int idx = threadIdx.x; idx < 16 * 32; idx += 256)
        W5l[(idx / 32) * 33 + (idx % 32)] = W5[idx];
    int wv = threadIdx.x >> 6, lane = threadIdx.x & 63;
    int node = blockIdx.x * 4 + wv;
    if (node < n) {
        float hv = h[(size_t)node * NHID + lane];
        float pn = nrm_in[node];
        tl[wv][lane] = artanh_clip(pn) / pn * hv;
    }
    __syncthreads();
    if (lane < 32 && node < n) {
        float acc = b4[lane];
        const float* wr = &W4l[lane * 65];
#pragma unroll
        for (int j = 0; j < 64; j++) acc = fmaf(tl[wv][j], wr[j], acc);
        zl[wv][lane] = fmaxf(acc, 0.f);
    }
    __syncthreads();
    if (node >= n) return;
    float y = 0.f;
    if (lane < 16) {
        float acc = b5[lane];
        const float* wr = &W5l[lane * 33];
#pragma unroll
        for (int i = 0; i < 32; i++) acc = fmaf(zl[wv][i], wr[i], acc);
        y = acc;
    }
    float mx = y;
#pragma unroll
    for (int mk = 1; mk < 16; mk <<= 1) mx = fmaxf(mx, __shfl_xor(mx, mk, 64));
    float ex = __expf(y - mx);
    float sm = ex;
#pragma unroll
    for (int mk = 1; mk < 16; mk <<= 1) sm += __shfl_xor(sm, mk, 64);
    if (lane < 16) out[(size_t)node * 16 + lane] = y - mx - __logf(sm);
}

extern "C" void kernel_launch(void* const* d_in, const int* in_sizes, int n_in,
                              void* d_out, int out_size, void* d_ws, size_t ws_size,
                              hipStream_t stream) {
    const float* x   = (const float*)d_in[0];
    const int*   src = (const int*)d_in[1];
    const int*   dst = (const int*)d_in[2];
    const float* adj = (const float*)d_in[3];
    const float* W1  = (const float*)d_in[4];  const float* b1 = (const float*)d_in[5];
    const float* W2  = (const float*)d_in[6];  const float* b2 = (const float*)d_in[7];
    const float* W3  = (const float*)d_in[8];  const float* b3 = (const float*)d_in[9];
    const float* W4  = (const float*)d_in[10]; const float* b4 = (const float*)d_in[11];
    const float* W5  = (const float*)d_in[12]; const float* b5 = (const float*)d_in[13];
    float* out = (float*)d_out;

    const int N = in_sizes[0] / NFEAT;
    const int E = in_sizes[1];

    // ws layout: ints, then 8B-aligned float2 edge stream, then float arrays
    int* off   = (int*)d_ws;            // N+1
    int* cnt   = off + (N + 1);         // N (histogram, then fill cursor)
    int* bsums = cnt + N;               // 1024
    size_t iofs = (size_t)(N + 1) + N + 1024;
    iofs = (iofs + 1) & ~(size_t)1;     // 8B align
    float2* pe = (float2*)((int*)d_ws + iofs);  // E  (src,adj) sorted by dst
    float* B    = (float*)(pe + E);     // ht     [N,64]
    float* D    = B + (size_t)N * NHID; // h      [N,64]
    float* nrm  = D + (size_t)N * NHID; // ||h||  [N]
    float* hbs  = nrm + N;              // 3*64 hyperbolic biases
    float* hbns = hbs + 192;            // 3 bias norms

    dim3 blk(256);
    int nodeBlocks = (N + 3) / 4;
    int edgeThBlocks = (E + 255) / 256;
    int nb = (N + SCAN_B - 1) / SCAN_B;

    // bias precompute + CSR build (once, reused by all 3 layers)
    k_bias<<<1, 192, 0, stream>>>(b1, b2, b3, hbs, hbns);
    hipMemsetAsync(cnt, 0, (size_t)N * sizeof(int), stream);
    k_hist<<<edgeThBlocks, blk, 0, stream>>>(dst, cnt, E);
    k_scan1<<<nb, blk, 0, stream>>>(cnt, off, bsums, N);
    k_scan2<<<1, blk, 0, stream>>>(bsums, nb, off, N);
    k_scan3<<<(N + 255) / 256, blk, 0, stream>>>(off, cnt, bsums, N);
    k_permute<<<edgeThBlocks, blk, 0, stream>>>(src, dst, adj, cnt, pe, E);

    // layer 1
    k_hyplin1<<<512, blk, 0, stream>>>(x, W1, hbs, hbns, B, N);
    k_agg_act<<<nodeBlocks, blk, 0, stream>>>(B, off, pe, D, nrm, N);
    // layer 2
    k_hyplin64<<<1024, blk, 0, stream>>>(D, nrm, W2, hbs + 64, hbns + 1, B, N);
    k_agg_act<<<nodeBlocks, blk, 0, stream>>>(B, off, pe, D, nrm, N);
    // layer 3
    k_hyplin64<<<1024, blk, 0, stream>>>(D, nrm, W3, hbs + 128, hbns + 2, B, N);
    k_agg_act<<<nodeBlocks, blk, 0, stream>>>(B, off, pe, D, nrm, N);

    // head
    k_head<<<nodeBlocks, blk, 0, stream>>>(D, nrm, W4, b4, W5, b5, out, N);
}

// Round 4
// 651.088 us; speedup vs baseline: 2.6396x; 1.1187x over previous
//
#include <hip/hip_runtime.h>
#include <hip/hip_bf16.h>
#include <math.h>

#define NFEAT 128
#define NHID  64
#define SCAN_B 1024

typedef __attribute__((ext_vector_type(8))) short short8;
typedef __attribute__((ext_vector_type(4))) float floatx4;

__device__ __forceinline__ float wave_sum(float v) {
#pragma unroll
    for (int m = 1; m < 64; m <<= 1) v += __shfl_xor(v, m, 64);
    return v;
}

__device__ __forceinline__ float fast_tanh(float x) {
    float e = __expf(2.f * x);
    return 1.f - 2.f / (e + 1.f);
}

__device__ __forceinline__ float artanh_clip(float v) {
    const float lim = 0.99999988f;  // float(1 - 1e-7)
    v = fminf(fmaxf(v, -lim), lim);
    return 0.5f * __logf((1.f + v) / (1.f - v));
}

__device__ __forceinline__ unsigned pack2(float a, float b) {
    __hip_bfloat16 x = __float2bfloat16(a), y = __float2bfloat16(b);
    unsigned short ux = *(unsigned short*)&x, uy = *(unsigned short*)&y;
    return (unsigned)ux | ((unsigned)uy << 16);
}

// HypLinear tail with analytic norms.
__device__ __forceinline__ float hyp_tail_fast(float mp, float pn,
        const float* __restrict__ hb, float hbn, int lane) {
    float mpn = sqrtf(wave_sum(mp * mp));
    float targ = (mpn / pn) * artanh_clip(pn);
    float th = fast_tanh(targ);
    float res = th * mp / fmaxf(mpn, 1e-15f);
    float rn = th;
    if (mpn <= 1e-15f) { res = 0.f; rn = 0.f; }
    if (rn > 0.996f) { res *= 0.996f / rn; rn = 0.996f; }
    float m = res, mn = rn;
    if (hbn > 1e-15f) {
        float hbv = hb[lane];
        float x2 = rn * rn, y2 = hbn * hbn;
        float xy = wave_sum(res * hbv);
        float num = (1.f + 2.f * xy + y2) * res + (1.f - x2) * hbv;
        float den = 1.f + 2.f * xy + x2 * y2;
        m = num / fmaxf(den, 1e-15f);
        mn = sqrtf(wave_sum(m * m));
        if (mn > 0.996f) { m *= 0.996f / mn; mn = 0.996f; }
    }
    float pn2 = fmaxf(mn, 1e-15f);
    return artanh_clip(pn2) / pn2 * m;
}

// ---- CSR build --------------------------------------------------------------

__global__ __launch_bounds__(256) void k_hist(const int* __restrict__ dst,
                                              int* __restrict__ cnt, int e) {
    int i = blockIdx.x * 256 + threadIdx.x;
    if (i < e) atomicAdd(&cnt[dst[i]], 1);
}

__global__ __launch_bounds__(256) void k_scan1(const int* __restrict__ cnt,
        int* __restrict__ off, int* __restrict__ bsums, int n) {
    __shared__ int s[256];
    int tid = threadIdx.x;
    int base = blockIdx.x * SCAN_B + tid * 4;
    int c0 = 0, c1 = 0, c2 = 0, c3 = 0;
    if (base + 0 < n) c0 = cnt[base + 0];
    if (base + 1 < n) c1 = cnt[base + 1];
    if (base + 2 < n) c2 = cnt[base + 2];
    if (base + 3 < n) c3 = cnt[base + 3];
    int tsum = c0 + c1 + c2 + c3;
    s[tid] = tsum; __syncthreads();
    for (int o = 1; o < 256; o <<= 1) {
        int v = (tid >= o) ? s[tid - o] : 0;
        __syncthreads();
        s[tid] += v;
        __syncthreads();
    }
    int excl = s[tid] - tsum;
    if (base + 0 < n) off[base + 0] = excl;
    if (base + 1 < n) off[base + 1] = excl + c0;
    if (base + 2 < n) off[base + 2] = excl + c0 + c1;
    if (base + 3 < n) off[base + 3] = excl + c0 + c1 + c2;
    if (tid == 255) bsums[blockIdx.x] = s[255];
}

__global__ __launch_bounds__(256) void k_scan2(int* __restrict__ bsums, int nb,
                                               int* __restrict__ off, int ntot) {
    __shared__ int s[256];
    int tid = threadIdx.x;
    int base = tid * 4;
    int c0 = 0, c1 = 0, c2 = 0, c3 = 0;
    if (base + 0 < nb) c0 = bsums[base + 0];
    if (base + 1 < nb) c1 = bsums[base + 1];
    if (base + 2 < nb) c2 = bsums[base + 2];
    if (base + 3 < nb) c3 = bsums[base + 3];
    int tsum = c0 + c1 + c2 + c3;
    s[tid] = tsum; __syncthreads();
    for (int o = 1; o < 256; o <<= 1) {
        int v = (tid >= o) ? s[tid - o] : 0;
        __syncthreads();
        s[tid] += v;
        __syncthreads();
    }
    int excl = s[tid] - tsum;
    if (base + 0 < nb) bsums[base + 0] = excl;
    if (base + 1 < nb) bsums[base + 1] = excl + c0;
    if (base + 2 < nb) bsums[base + 2] = excl + c0 + c1;
    if (base + 3 < nb) bsums[base + 3] = excl + c0 + c1 + c2;
    if (tid == 255) off[ntot] = s[255];
}

__global__ __launch_bounds__(256) void k_scan3(int* __restrict__ off,
        int* __restrict__ ptr, const int* __restrict__ bsums, int n) {
    int i = blockIdx.x * 256 + threadIdx.x;
    if (i < n) {
        int v = off[i] + bsums[i >> 10];
        off[i] = v;
        ptr[i] = v;
    }
}

__global__ __launch_bounds__(256) void k_permute(const int* __restrict__ src,
        const int* __restrict__ dst, const float* __restrict__ adj,
        int* __restrict__ ptr, float2* __restrict__ pe, int e) {
    int i = blockIdx.x * 256 + threadIdx.x;
    if (i < e) {
        int d = dst[i];
        int pos = atomicAdd(&ptr[d], 1);
        pe[pos] = make_float2(__int_as_float(src[i]), adj[i]);
    }
}

// hyperbolic bias per layer
__global__ __launch_bounds__(192) void k_bias(const float* __restrict__ b1,
        const float* __restrict__ b2, const float* __restrict__ b3,
        float* __restrict__ hbs, float* __restrict__ hbns) {
    int wv = threadIdx.x >> 6, lane = threadIdx.x & 63;
    const float* b = (wv == 0) ? b1 : (wv == 1) ? b2 : b3;
    float bv = b[lane];
    float bn = fmaxf(sqrtf(wave_sum(bv * bv)), 1e-15f);
    float th = fast_tanh(bn);
    float f = th / bn;
    float hn = th;
    if (th > 0.996f) { f = 0.996f / bn; hn = 0.996f; }
    hbs[wv * 64 + lane] = bv * f;
    if (lane == 0) hbns[wv] = hn;
}

// pack W [64 out, K in] into MFMA B-fragment order (bf16):
// Bpk[(((ks*4+hi)*4+nf)*16+c)*8 + j] = W[nf*16+c][ks*32+hi*8+j]
__global__ __launch_bounds__(256) void k_wcvt(const float* __restrict__ W, int K,
                                              unsigned short* __restrict__ Bpk) {
    int tot = 64 * K;
    for (int o = blockIdx.x * 256 + threadIdx.x; o < tot; o += gridDim.x * 256) {
        int j = o & 7, c = (o >> 3) & 15, nf = (o >> 7) & 3, hi = (o >> 9) & 3,
            ks = o >> 11;
        int k = ks * 32 + hi * 8 + j;
        int col = nf * 16 + c;
        __hip_bfloat16 b = __float2bfloat16(W[col * K + k]);
        Bpk[o] = *(unsigned short*)&b;
    }
}

// ---- MFMA GEMM: mp[N,64] = A[N,K] @ W^T (A optionally expmap0+proj fused) ---
template <int K, bool EXP0>
__global__ __launch_bounds__(256) void k_gemm(
        const float* __restrict__ A, const unsigned short* __restrict__ Bpk,
        float* __restrict__ mp, float* __restrict__ nrm0, int n) {
    constexpr int KS = K / 32;
    constexpr int RB = K * 2;  // LDS row bytes (bf16)
    __shared__ __align__(16) unsigned char As[64 * RB];
    int tid = threadIdx.x;
    int wv = tid >> 6, lane = tid & 63;
    int rowBase = blockIdx.x * 64;

    if (EXP0) {
        // K=128: one row per wave-instr; lane covers cols 2*lane, 2*lane+1
#pragma unroll
        for (int it = 0; it < 16; ++it) {
            int row = wv * 16 + it;
            int rg = rowBase + row;
            float2 v = make_float2(0.f, 0.f);
            if (rg < n) v = *(const float2*)(A + (size_t)rg * K + lane * 2);
            float ss = wave_sum(v.x * v.x + v.y * v.y);
            float nr = fmaxf(sqrtf(ss), 1e-15f);
            float th = fast_tanh(nr);
            float f = th / nr;
            float pn = fmaxf(th, 1e-15f);
            if (th > 0.996f) { f = 0.996f / nr; pn = 0.996f; }
            unsigned pk = pack2(v.x * f, v.y * f);
            unsigned byte = (unsigned)(row * RB + lane * 4) ^ ((row & 7) << 4);
            *(unsigned*)(As + byte) = pk;
            if (lane == 0 && rg < n) nrm0[rg] = pn;
        }
    } else {
        // K=64: two rows per wave-instr
#pragma unroll
        for (int it = 0; it < 8; ++it) {
            int row = wv * 16 + it * 2 + (lane >> 5);
            int rg = rowBase + row;
            int cl = lane & 31;
            float2 v = make_float2(0.f, 0.f);
            if (rg < n) v = *(const float2*)(A + (size_t)rg * K + cl * 2);
            unsigned pk = pack2(v.x, v.y);
            unsigned byte = (unsigned)(row * RB + cl * 4) ^ ((row & 7) << 4);
            *(unsigned*)(As + byte) = pk;
        }
    }
    __syncthreads();

    int hi = lane >> 4, c = lane & 15;
    // B fragments (prepacked, same k-slot order as A below)
    short8 bf[KS][4];
#pragma unroll
    for (int ks = 0; ks < KS; ++ks)
#pragma unroll
        for (int nf = 0; nf < 4; ++nf)
            bf[ks][nf] =
                *(const short8*)(Bpk + (((size_t)(ks * 4 + hi) * 4 + nf) * 16 + c) * 8);

    floatx4 acc[4];
#pragma unroll
    for (int nf = 0; nf < 4; ++nf)
#pragma unroll
        for (int r = 0; r < 4; ++r) acc[nf][r] = 0.f;

    int arow = wv * 16 + c;
#pragma unroll
    for (int ks = 0; ks < KS; ++ks) {
        unsigned byte = (unsigned)(arow * RB + ks * 64 + hi * 16) ^ ((arow & 7) << 4);
        short8 af = *(const short8*)(As + byte);
#pragma unroll
        for (int nf = 0; nf < 4; ++nf)
            acc[nf] = __builtin_amdgcn_mfma_f32_16x16x32_bf16(af, bf[ks][nf],
                                                              acc[nf], 0, 0, 0);
    }

    // epilogue: C row = (lane>>4)*4+reg, col = nf*16 + (lane&15)   [m89-verified]
#pragma unroll
    for (int nf = 0; nf < 4; ++nf)
#pragma unroll
        for (int r = 0; r < 4; ++r) {
            int rg = rowBase + wv * 16 + hi * 4 + r;
            if (rg < n) mp[(size_t)rg * 64 + nf * 16 + c] = acc[nf][r];
        }
}

// in-place: mp row -> ht row (HypLinear tail + logmap0)
__global__ __launch_bounds__(256) void k_tail(
        float* __restrict__ m_io, const float* __restrict__ nrm_in,
        const float* __restrict__ hb, const float* __restrict__ hbn_p, int n) {
    int wv = threadIdx.x >> 6, lane = threadIdx.x & 63;
    int node = blockIdx.x * 4 + wv;
    if (node >= n) return;
    float hbn = hbn_p[0];
    float mp = m_io[(size_t)node * NHID + lane];
    float pn = nrm_in[node];
    m_io[(size_t)node * NHID + lane] = hyp_tail_fast(mp, pn, hb, hbn, lane);
}

// CSR aggregation + HypAct
__global__ __launch_bounds__(256) void k_agg_act(
        const float* __restrict__ ht, const int* __restrict__ off,
        const float2* __restrict__ pe, float* __restrict__ hout,
        float* __restrict__ nrm_out, int n) {
    int wv = threadIdx.x >> 6, lane = threadIdx.x & 63;
    int node = blockIdx.x * 4 + wv;
    if (node >= n) return;
    node = __builtin_amdgcn_readfirstlane(node);
    int beg = off[node], end = off[node + 1];
    float acc = 0.f;
    int e = beg;
    for (; e + 1 < end; e += 2) {
        float2 p0 = pe[e], p1 = pe[e + 1];
        int s0 = __float_as_int(p0.x), s1 = __float_as_int(p1.x);
        acc = fmaf(p0.y, ht[(size_t)s0 * NHID + lane], acc);
        acc = fmaf(p1.y, ht[(size_t)s1 * NHID + lane], acc);
    }
    if (e < end) {
        float2 p0 = pe[e];
        acc = fmaf(p0.y, ht[(size_t)__float_as_int(p0.x) * NHID + lane], acc);
    }
    float un = fmaxf(sqrtf(wave_sum(acc * acc)), 1e-15f);
    float thu = fast_tanh(un);
    float p = thu / un * acc;
    float pn = fmaxf(thu, 1e-15f);
    if (thu > 0.996f) { p *= 0.996f / thu; pn = 0.996f; }
    float t = artanh_clip(pn) / pn * p;
    t = fmaxf(t, 0.f);
    float tn = fmaxf(sqrtf(wave_sum(t * t)), 1e-15f);
    float tht = fast_tanh(tn);
    float r = tht / tn * t;
    float rn = fmaxf(tht, 1e-15f);
    if (tht > 0.996f) { r *= 0.996f / tht; rn = 0.996f; }
    hout[(size_t)node * NHID + lane] = r;
    if (lane == 0) nrm_out[node] = rn;
}

// head
__global__ __launch_bounds__(256) void k_head(
        const float* __restrict__ h, const float* __restrict__ nrm_in,
        const float* __restrict__ W4, const float* __restrict__ b4,
        const float* __restrict__ W5, const float* __restrict__ b5,
        float* __restrict__ out, int n) {
    __shared__ float W4l[32 * 65];
    __shared__ float W5l[16 * 33];
    __shared__ float tl[4][64];
    __shared__ float zl[4][33];
    for (int idx = threadIdx.x; idx < 32 * 64; idx += 256)
        W4l[(idx / 64) * 65 + (idx % 64)] = W4[idx];
    for (int idx = threadIdx.x; idx < 16 * 32; idx += 256)
        W5l[(idx / 32) * 33 + (idx % 32)] = W5[idx];
    int wv = threadIdx.x >> 6, lane = threadIdx.x & 63;
    int node = blockIdx.x * 4 + wv;
    if (node < n) {
        float hv = h[(size_t)node * NHID + lane];
        float pn = nrm_in[node];
        tl[wv][lane] = artanh_clip(pn) / pn * hv;
    }
    __syncthreads();
    if (lane < 32 && node < n) {
        float acc = b4[lane];
        const float* wr = &W4l[lane * 65];
#pragma unroll
        for (int j = 0; j < 64; j++) acc = fmaf(tl[wv][j], wr[j], acc);
        zl[wv][lane] = fmaxf(acc, 0.f);
    }
    __syncthreads();
    if (node >= n) return;
    float y = 0.f;
    if (lane < 16) {
        float acc = b5[lane];
        const float* wr = &W5l[lane * 33];
#pragma unroll
        for (int i = 0; i < 32; i++) acc = fmaf(zl[wv][i], wr[i], acc);
        y = acc;
    }
    float mx = y;
#pragma unroll
    for (int mk = 1; mk < 16; mk <<= 1) mx = fmaxf(mx, __shfl_xor(mx, mk, 64));
    float ex = __expf(y - mx);
    float sm = ex;
#pragma unroll
    for (int mk = 1; mk < 16; mk <<= 1) sm += __shfl_xor(sm, mk, 64);
    if (lane < 16) out[(size_t)node * 16 + lane] = y - mx - __logf(sm);
}

extern "C" void kernel_launch(void* const* d_in, const int* in_sizes, int n_in,
                              void* d_out, int out_size, void* d_ws, size_t ws_size,
                              hipStream_t stream) {
    const float* x   = (const float*)d_in[0];
    const int*   src = (const int*)d_in[1];
    const int*   dst = (const int*)d_in[2];
    const float* adj = (const float*)d_in[3];
    const float* W1  = (const float*)d_in[4];  const float* b1 = (const float*)d_in[5];
    const float* W2  = (const float*)d_in[6];  const float* b2 = (const float*)d_in[7];
    const float* W3  = (const float*)d_in[8];  const float* b3 = (const float*)d_in[9];
    const float* W4  = (const float*)d_in[10]; const float* b4 = (const float*)d_in[11];
    const float* W5  = (const float*)d_in[12]; const float* b5 = (const float*)d_in[13];
    float* out = (float*)d_out;

    const int N = in_sizes[0] / NFEAT;
    const int E = in_sizes[1];

    // ws layout
    int* off   = (int*)d_ws;            // N+1
    int* cnt   = off + (N + 1);         // N
    int* bsums = cnt + N;               // 1024
    size_t iofs = (size_t)(N + 1) + N + 1024;
    iofs = (iofs + 1) & ~(size_t)1;     // 8B align
    float2* pe = (float2*)((int*)d_ws + iofs);   // E
    float* B    = (float*)(pe + E);     // mp/ht  [N,64]
    float* D    = B + (size_t)N * NHID; // h      [N,64]
    float* nrm  = D + (size_t)N * NHID; // ||h||  [N]
    float* hbs  = nrm + N;              // 3*64
    float* hbns = hbs + 192;            // 3 (+1 pad)
    unsigned short* Bpk1 = (unsigned short*)(hbns + 4);  // 8192 ush (16B-aligned)
    unsigned short* Bpk2 = Bpk1 + 8192;                  // 4096
    unsigned short* Bpk3 = Bpk2 + 4096;                  // 4096

    dim3 blk(256);
    int nodeBlocks = (N + 3) / 4;
    int gemmBlocks = (N + 63) / 64;
    int edgeThBlocks = (E + 255) / 256;
    int nb = (N + SCAN_B - 1) / SCAN_B;

    // prep: bias orbits + W packs + CSR
    k_bias<<<1, 192, 0, stream>>>(b1, b2, b3, hbs, hbns);
    k_wcvt<<<32, blk, 0, stream>>>(W1, 128, Bpk1);
    k_wcvt<<<16, blk, 0, stream>>>(W2, 64, Bpk2);
    k_wcvt<<<16, blk, 0, stream>>>(W3, 64, Bpk3);
    hipMemsetAsync(cnt, 0, (size_t)N * sizeof(int), stream);
    k_hist<<<edgeThBlocks, blk, 0, stream>>>(dst, cnt, E);
    k_scan1<<<nb, blk, 0, stream>>>(cnt, off, bsums, N);
    k_scan2<<<1, blk, 0, stream>>>(bsums, nb, off, N);
    k_scan3<<<(N + 255) / 256, blk, 0, stream>>>(off, cnt, bsums, N);
    k_permute<<<edgeThBlocks, blk, 0, stream>>>(src, dst, adj, cnt, pe, E);

    // layer 1 (fused expmap0(x)+proj inside GEMM staging)
    k_gemm<128, true><<<gemmBlocks, blk, 0, stream>>>(x, Bpk1, B, nrm, N);
    k_tail<<<nodeBlocks, blk, 0, stream>>>(B, nrm, hbs, hbns, N);
    k_agg_act<<<nodeBlocks, blk, 0, stream>>>(B, off, pe, D, nrm, N);
    // layer 2
    k_gemm<64, false><<<gemmBlocks, blk, 0, stream>>>(D, Bpk2, B, nullptr, N);
    k_tail<<<nodeBlocks, blk, 0, stream>>>(B, nrm, hbs + 64, hbns + 1, N);
    k_agg_act<<<nodeBlocks, blk, 0, stream>>>(B, off, pe, D, nrm, N);
    // layer 3
    k_gemm<64, false><<<gemmBlocks, blk, 0, stream>>>(D, Bpk3, B, nullptr, N);
    k_tail<<<nodeBlocks, blk, 0, stream>>>(B, nrm, hbs + 128, hbns + 2, N);
    k_agg_act<<<nodeBlocks, blk, 0, stream>>>(B, off, pe, D, nrm, N);

    // head
    k_head<<<nodeBlocks, blk, 0, stream>>>(D, nrm, W4, b4, W5, b5, out, N);
}

// Round 5
// 522.395 us; speedup vs baseline: 3.2899x; 1.2464x over previous
//
#include <hip/hip_runtime.h>
#include <hip/hip_bf16.h>
#include <math.h>

#define NFEAT 128
#define NHID  64
#define SCAN_B 1024
#define ATH996 3.106303f   // artanh(0.996)

typedef __attribute__((ext_vector_type(8))) short short8;
typedef __attribute__((ext_vector_type(4))) float floatx4;
typedef unsigned short ushort_t;

__device__ __forceinline__ float wave_sum(float v) {
#pragma unroll
    for (int m = 1; m < 64; m <<= 1) v += __shfl_xor(v, m, 64);
    return v;
}

__device__ __forceinline__ float fast_tanh(float x) {
    float e = __expf(2.f * x);
    return 1.f - 2.f / (e + 1.f);
}

__device__ __forceinline__ float artanh_clip(float v) {
    const float lim = 0.99999988f;  // float(1 - 1e-7)
    v = fminf(fmaxf(v, -lim), lim);
    return 0.5f * __logf((1.f + v) / (1.f - v));
}

__device__ __forceinline__ unsigned pack2(float a, float b) {
    __hip_bfloat16 x = __float2bfloat16(a), y = __float2bfloat16(b);
    ushort_t ux = *(ushort_t*)&x, uy = *(ushort_t*)&y;
    return (unsigned)ux | ((unsigned)uy << 16);
}

__device__ __forceinline__ float bf2f(ushort_t u) {
    return __uint_as_float(((unsigned)u) << 16);
}
__device__ __forceinline__ ushort_t f2bf(float f) {
    __hip_bfloat16 h = __float2bfloat16(f);
    return *(ushort_t*)&h;
}

// ---- CSR build --------------------------------------------------------------

// local rank within dst segment + histogram (replaces k_hist)
__global__ __launch_bounds__(256) void k_rank(const int* __restrict__ dst,
        int* __restrict__ cnt, int* __restrict__ lr, int e) {
    int i = blockIdx.x * 256 + threadIdx.x;
    if (i < e) lr[i] = atomicAdd(&cnt[dst[i]], 1);
}

__global__ __launch_bounds__(256) void k_scan1(const int* __restrict__ cnt,
        int* __restrict__ off, int* __restrict__ bsums, int n) {
    __shared__ int s[256];
    int tid = threadIdx.x;
    int base = blockIdx.x * SCAN_B + tid * 4;
    int c0 = 0, c1 = 0, c2 = 0, c3 = 0;
    if (base + 0 < n) c0 = cnt[base + 0];
    if (base + 1 < n) c1 = cnt[base + 1];
    if (base + 2 < n) c2 = cnt[base + 2];
    if (base + 3 < n) c3 = cnt[base + 3];
    int tsum = c0 + c1 + c2 + c3;
    s[tid] = tsum; __syncthreads();
    for (int o = 1; o < 256; o <<= 1) {
        int v = (tid >= o) ? s[tid - o] : 0;
        __syncthreads();
        s[tid] += v;
        __syncthreads();
    }
    int excl = s[tid] - tsum;
    if (base + 0 < n) off[base + 0] = excl;
    if (base + 1 < n) off[base + 1] = excl + c0;
    if (base + 2 < n) off[base + 2] = excl + c0 + c1;
    if (base + 3 < n) off[base + 3] = excl + c0 + c1 + c2;
    if (tid == 255) bsums[blockIdx.x] = s[255];
}

__global__ __launch_bounds__(256) void k_scan2(int* __restrict__ bsums, int nb,
                                               int* __restrict__ off, int ntot) {
    __shared__ int s[256];
    int tid = threadIdx.x;
    int base = tid * 4;
    int c0 = 0, c1 = 0, c2 = 0, c3 = 0;
    if (base + 0 < nb) c0 = bsums[base + 0];
    if (base + 1 < nb) c1 = bsums[base + 1];
    if (base + 2 < nb) c2 = bsums[base + 2];
    if (base + 3 < nb) c3 = bsums[base + 3];
    int tsum = c0 + c1 + c2 + c3;
    s[tid] = tsum; __syncthreads();
    for (int o = 1; o < 256; o <<= 1) {
        int v = (tid >= o) ? s[tid - o] : 0;
        __syncthreads();
        s[tid] += v;
        __syncthreads();
    }
    int excl = s[tid] - tsum;
    if (base + 0 < nb) bsums[base + 0] = excl;
    if (base + 1 < nb) bsums[base + 1] = excl + c0;
    if (base + 2 < nb) bsums[base + 2] = excl + c0 + c1;
    if (base + 3 < nb) bsums[base + 3] = excl + c0 + c1 + c2;
    if (tid == 255) off[ntot] = s[255];
}

__global__ __launch_bounds__(256) void k_scan3(int* __restrict__ off,
        const int* __restrict__ bsums, int n) {
    int i = blockIdx.x * 256 + threadIdx.x;
    if (i < n) off[i] += bsums[i >> 10];
}

// inverse permutation: inv[finalpos] = edge index (4B scatter)
__global__ __launch_bounds__(256) void k_build(const int* __restrict__ dst,
        const int* __restrict__ off, const int* __restrict__ lr,
        int* __restrict__ inv, int e) {
    int i = blockIdx.x * 256 + threadIdx.x;
    if (i < e) inv[off[dst[i]] + lr[i]] = i;
}

// coalesced build of (src, adj) stream sorted by dst
__global__ __launch_bounds__(256) void k_gather(const int* __restrict__ src,
        const float* __restrict__ adj, const int* __restrict__ inv,
        float2* __restrict__ pe, int e) {
    int p = blockIdx.x * 256 + threadIdx.x;
    if (p < e) {
        int i = inv[p];
        pe[p] = make_float2(__int_as_float(src[i]), adj[i]);
    }
}

// hyperbolic bias per layer
__global__ __launch_bounds__(192) void k_bias(const float* __restrict__ b1,
        const float* __restrict__ b2, const float* __restrict__ b3,
        float* __restrict__ hbs, float* __restrict__ hbns) {
    int wv = threadIdx.x >> 6, lane = threadIdx.x & 63;
    const float* b = (wv == 0) ? b1 : (wv == 1) ? b2 : b3;
    float bv = b[lane];
    float bn = fmaxf(sqrtf(wave_sum(bv * bv)), 1e-15f);
    float th = fast_tanh(bn);
    float f = th / bn;
    float hn = th;
    if (th > 0.996f) { f = 0.996f / bn; hn = 0.996f; }
    hbs[wv * 64 + lane] = bv * f;
    if (lane == 0) hbns[wv] = hn;
}

// pack W [64 out, K in] into MFMA B-fragment order (bf16)
__global__ __launch_bounds__(256) void k_wcvt(const float* __restrict__ W, int K,
                                              ushort_t* __restrict__ Bpk) {
    int tot = 64 * K;
    for (int o = blockIdx.x * 256 + threadIdx.x; o < tot; o += gridDim.x * 256) {
        int j = o & 7, c = (o >> 3) & 15, nf = (o >> 7) & 3, hi = (o >> 9) & 3,
            ks = o >> 11;
        int k = ks * 32 + hi * 8 + j;
        int col = nf * 16 + c;
        Bpk[o] = f2bf(W[col * K + k]);
    }
}

// epilogue transform shared by both GEMMs: one row of mp (4 vals/lane across
// nf), 16-lane group reduction, HypLinear tail collapsed analytically.
__device__ __forceinline__ void epi_row(const floatx4* acc, int r, float pn,
        float hbn, const float* __restrict__ hb, int c, float outv[4]) {
    float pp = 0.f;
#pragma unroll
    for (int nf = 0; nf < 4; ++nf) pp += acc[nf][r] * acc[nf][r];
#pragma unroll
    for (int m = 1; m < 16; m <<= 1) pp += __shfl_xor(pp, m, 64);
    float mpn = sqrtf(pp);
    float an = artanh_clip(pn);
    if (hbn <= 1e-15f) {
        float targ = (mpn / pn) * an;
        float scale = (targ > ATH996) ? (ATH996 / mpn) : (an / pn);
        if (mpn <= 1e-15f) scale = 0.f;
#pragma unroll
        for (int nf = 0; nf < 4; ++nf) outv[nf] = acc[nf][r] * scale;
    } else {
        float targ = (mpn / pn) * an;
        float th = fast_tanh(targ);
        float rn = fminf(th, 0.996f);
        float rs = (mpn <= 1e-15f) ? 0.f : (rn / mpn);
        float res[4], xyp = 0.f;
#pragma unroll
        for (int nf = 0; nf < 4; ++nf) {
            res[nf] = acc[nf][r] * rs;
            xyp += res[nf] * hb[nf * 16 + c];
        }
#pragma unroll
        for (int m = 1; m < 16; m <<= 1) xyp += __shfl_xor(xyp, m, 64);
        float x2 = rn * rn, y2 = hbn * hbn;
        float den = fmaxf(1.f + 2.f * xyp + x2 * y2, 1e-15f);
        float ca = (1.f + 2.f * xyp + y2) / den, cb = (1.f - x2) / den;
        float mv[4], mm = 0.f;
#pragma unroll
        for (int nf = 0; nf < 4; ++nf) {
            mv[nf] = ca * res[nf] + cb * hb[nf * 16 + c];
            mm += mv[nf] * mv[nf];
        }
#pragma unroll
        for (int m = 1; m < 16; m <<= 1) mm += __shfl_xor(mm, m, 64);
        float mn = sqrtf(mm);
        float mc = fminf(fmaxf(mn, 1e-15f), 0.996f);
        float msc = ((mn > 0.996f) ? (0.996f / mn) : 1.f) * artanh_clip(mc) / mc;
#pragma unroll
        for (int nf = 0; nf < 4; ++nf) outv[nf] = mv[nf] * msc;
    }
}

// layer 1 GEMM: x fp32 [N,128] -> (expmap0+proj fused) -> MFMA -> tail -> ht bf16
__global__ __launch_bounds__(256) void k_gemm1(
        const float* __restrict__ x, const ushort_t* __restrict__ Bpk,
        const float* __restrict__ hb, const float* __restrict__ hbn_p,
        ushort_t* __restrict__ htout, int n) {
    constexpr int RB = 256;
    __shared__ __align__(16) unsigned char As[64 * RB];
    __shared__ float pns[64];
    int tid = threadIdx.x, wv = tid >> 6, lane = tid & 63;
    int rowBase = blockIdx.x * 64;
#pragma unroll
    for (int it = 0; it < 16; ++it) {
        int row = wv * 16 + it, rg = rowBase + row;
        float2 v = make_float2(0.f, 0.f);
        if (rg < n) v = *(const float2*)(x + (size_t)rg * NFEAT + lane * 2);
        float ss = wave_sum(v.x * v.x + v.y * v.y);
        float nr = fmaxf(sqrtf(ss), 1e-15f);
        float th = fast_tanh(nr);
        float f = th / nr;
        float pn = fmaxf(th, 1e-15f);
        if (th > 0.996f) { f = 0.996f / nr; pn = 0.996f; }
        unsigned byte = (unsigned)(row * RB + lane * 4) ^ ((row & 7) << 4);
        *(unsigned*)(As + byte) = pack2(v.x * f, v.y * f);
        if (lane == 0) pns[row] = pn;
    }
    // no barrier: each wave stages and consumes its own 16 rows
    int hi = lane >> 4, c = lane & 15;
    short8 bf[4][4];
#pragma unroll
    for (int ks = 0; ks < 4; ++ks)
#pragma unroll
        for (int nf = 0; nf < 4; ++nf)
            bf[ks][nf] = *(const short8*)(Bpk + (((size_t)(ks * 4 + hi) * 4 + nf) * 16 + c) * 8);
    floatx4 acc[4];
#pragma unroll
    for (int nf = 0; nf < 4; ++nf)
#pragma unroll
        for (int r = 0; r < 4; ++r) acc[nf][r] = 0.f;
    int arow = wv * 16 + c;
#pragma unroll
    for (int ks = 0; ks < 4; ++ks) {
        unsigned byte = (unsigned)(arow * RB + ks * 64 + hi * 16) ^ ((arow & 7) << 4);
        short8 af = *(const short8*)(As + byte);
#pragma unroll
        for (int nf = 0; nf < 4; ++nf)
            acc[nf] = __builtin_amdgcn_mfma_f32_16x16x32_bf16(af, bf[ks][nf], acc[nf], 0, 0, 0);
    }
    float hbn = hbn_p[0];
#pragma unroll
    for (int r = 0; r < 4; ++r) {
        int row = wv * 16 + hi * 4 + r, rg = rowBase + row;
        float outv[4];
        epi_row(acc, r, pns[row], hbn, hb, c, outv);
        if (rg < n) {
#pragma unroll
            for (int nf = 0; nf < 4; ++nf)
                htout[(size_t)rg * 64 + nf * 16 + c] = f2bf(outv[nf]);
        }
    }
}

// layers 2/3 GEMM: h bf16 [N,64] (+ nrm fp32) -> MFMA -> tail -> ht bf16
__global__ __launch_bounds__(256) void k_gemm64(
        const ushort_t* __restrict__ h, const float* __restrict__ nrm_in,
        const ushort_t* __restrict__ Bpk, const float* __restrict__ hb,
        const float* __restrict__ hbn_p, ushort_t* __restrict__ htout, int n) {
    constexpr int RB = 128;
    __shared__ __align__(16) unsigned char As[64 * RB];
    int tid = threadIdx.x, wv = tid >> 6, lane = tid & 63;
    int rowBase = blockIdx.x * 64;
#pragma unroll
    for (int it = 0; it < 8; ++it) {
        int row = wv * 16 + it * 2 + (lane >> 5), rg = rowBase + row;
        int cl = lane & 31;
        unsigned pk = 0;
        if (rg < n) pk = *(const unsigned*)(h + (size_t)rg * 64 + cl * 2);
        unsigned byte = (unsigned)(row * RB + cl * 4) ^ ((row & 7) << 4);
        *(unsigned*)(As + byte) = pk;
    }
    int hi = lane >> 4, c = lane & 15;
    short8 bf[2][4];
#pragma unroll
    for (int ks = 0; ks < 2; ++ks)
#pragma unroll
        for (int nf = 0; nf < 4; ++nf)
            bf[ks][nf] = *(const short8*)(Bpk + (((size_t)(ks * 4 + hi) * 4 + nf) * 16 + c) * 8);
    floatx4 acc[4];
#pragma unroll
    for (int nf = 0; nf < 4; ++nf)
#pragma unroll
        for (int r = 0; r < 4; ++r) acc[nf][r] = 0.f;
    int arow = wv * 16 + c;
#pragma unroll
    for (int ks = 0; ks < 2; ++ks) {
        unsigned byte = (unsigned)(arow * RB + ks * 64 + hi * 16) ^ ((arow & 7) << 4);
        short8 af = *(const short8*)(As + byte);
#pragma unroll
        for (int nf = 0; nf < 4; ++nf)
            acc[nf] = __builtin_amdgcn_mfma_f32_16x16x32_bf16(af, bf[ks][nf], acc[nf], 0, 0, 0);
    }
    float hbn = hbn_p[0];
#pragma unroll
    for (int r = 0; r < 4; ++r) {
        int row = wv * 16 + hi * 4 + r, rg = rowBase + row;
        float pn = (rg < n) ? nrm_in[rg] : 1e-15f;
        float outv[4];
        epi_row(acc, r, pn, hbn, hb, c, outv);
        if (rg < n) {
#pragma unroll
            for (int nf = 0; nf < 4; ++nf)
                htout[(size_t)rg * 64 + nf * 16 + c] = f2bf(outv[nf]);
        }
    }
}

// CSR aggregation (bf16 gathers) + HypAct. TANGENT_OUT: emit head tangent vec.
template <bool TANGENT_OUT>
__global__ __launch_bounds__(256) void k_agg_act(
        const ushort_t* __restrict__ ht, const int* __restrict__ off,
        const float2* __restrict__ pe, ushort_t* __restrict__ hout,
        float* __restrict__ nrm_out, int n) {
    int wv = threadIdx.x >> 6, lane = threadIdx.x & 63;
    int node = blockIdx.x * 4 + wv;
    if (node >= n) return;
    node = __builtin_amdgcn_readfirstlane(node);
    int beg = off[node], end = off[node + 1];
    float acc = 0.f, acc2 = 0.f;
    int e = beg;
    for (; e + 1 < end; e += 2) {
        float2 p0 = pe[e], p1 = pe[e + 1];
        int s0 = __float_as_int(p0.x), s1 = __float_as_int(p1.x);
        acc  = fmaf(p0.y, bf2f(ht[(size_t)s0 * 64 + lane]), acc);
        acc2 = fmaf(p1.y, bf2f(ht[(size_t)s1 * 64 + lane]), acc2);
    }
    if (e < end) {
        float2 p0 = pe[e];
        acc = fmaf(p0.y, bf2f(ht[(size_t)__float_as_int(p0.x) * 64 + lane]), acc);
    }
    acc += acc2;
    float un = fmaxf(sqrtf(wave_sum(acc * acc)), 1e-15f);
    float thu = fast_tanh(un);
    float pf = thu / un, pn = thu;
    if (thu > 0.996f) { pf = 0.996f / un; pn = 0.996f; }
    float pnc = fmaxf(pn, 1e-15f);
    float t = artanh_clip(pnc) / pnc * pf * acc;   // logmap0(proj(expmap0(acc)))
    t = fmaxf(t, 0.f);                              // relu
    float tn = fmaxf(sqrtf(wave_sum(t * t)), 1e-15f);
    if (TANGENT_OUT) {
        // logmap0(proj(expmap0(t))) cancels unless the proj clips
        float o = (tn > ATH996) ? (ATH996 / tn) * t : t;
        hout[(size_t)node * 64 + lane] = f2bf(o);
    } else {
        float tht = fast_tanh(tn);
        float rf = tht / tn, rn = tht;
        if (tht > 0.996f) { rf = 0.996f / tn; rn = 0.996f; }
        hout[(size_t)node * 64 + lane] = f2bf(rf * t);
        if (lane == 0) nrm_out[node] = fmaxf(rn, 1e-15f);
    }
}

// head: z = relu(t@W4.T+b4); out = log_softmax(z@W5.T+b5)   (t given, bf16)
__global__ __launch_bounds__(256) void k_head(
        const ushort_t* __restrict__ t_in, const float* __restrict__ W4,
        const float* __restrict__ b4, const float* __restrict__ W5,
        const float* __restrict__ b5, float* __restrict__ out, int n) {
    __shared__ float W4l[32 * 65];
    __shared__ float W5l[16 * 33];
    __shared__ float tl[4][64];
    __shared__ float zl[4][33];
    for (int idx = threadIdx.x; idx < 32 * 64; idx += 256)
        W4l[(idx / 64) * 65 + (idx % 64)] = W4[idx];
    for (int idx = threadIdx.x; idx < 16 * 32; idx += 256)
        W5l[(idx / 32) * 33 + (idx % 32)] = W5[idx];
    int wv = threadIdx.x >> 6, lane = threadIdx.x & 63;
    int node = blockIdx.x * 4 + wv;
    if (node < n) tl[wv][lane] = bf2f(t_in[(size_t)node * 64 + lane]);
    __syncthreads();
    if (lane < 32 && node < n) {
        float acc = b4[lane];
        const float* wr = &W4l[lane * 65];
#pragma unroll
        for (int j = 0; j < 64; j++) acc = fmaf(tl[wv][j], wr[j], acc);
        zl[wv][lane] = fmaxf(acc, 0.f);
    }
    __syncthreads();
    if (node >= n) return;
    float y = 0.f;
    if (lane < 16) {
        float acc = b5[lane];
        const float* wr = &W5l[lane * 33];
#pragma unroll
        for (int i = 0; i < 32; i++) acc = fmaf(zl[wv][i], wr[i], acc);
        y = acc;
    }
    float mx = y;
#pragma unroll
    for (int mk = 1; mk < 16; mk <<= 1) mx = fmaxf(mx, __shfl_xor(mx, mk, 64));
    float ex = __expf(y - mx);
    float sm = ex;
#pragma unroll
    for (int mk = 1; mk < 16; mk <<= 1) sm += __shfl_xor(sm, mk, 64);
    if (lane < 16) out[(size_t)node * 16 + lane] = y - mx - __logf(sm);
}

extern "C" void kernel_launch(void* const* d_in, const int* in_sizes, int n_in,
                              void* d_out, int out_size, void* d_ws, size_t ws_size,
                              hipStream_t stream) {
    const float* x   = (const float*)d_in[0];
    const int*   src = (const int*)d_in[1];
    const int*   dst = (const int*)d_in[2];
    const float* adj = (const float*)d_in[3];
    const float* W1  = (const float*)d_in[4];  const float* b1 = (const float*)d_in[5];
    const float* W2  = (const float*)d_in[6];  const float* b2 = (const float*)d_in[7];
    const float* W3  = (const float*)d_in[8];  const float* b3 = (const float*)d_in[9];
    const float* W4  = (const float*)d_in[10]; const float* b4 = (const float*)d_in[11];
    const float* W5  = (const float*)d_in[12]; const float* b5 = (const float*)d_in[13];
    float* out = (float*)d_out;

    const int N = in_sizes[0] / NFEAT;
    const int E = in_sizes[1];

    // ws layout
    int* off   = (int*)d_ws;            // N+1
    int* cnt   = off + (N + 1);         // N
    int* bsums = cnt + N;               // 1024
    int* lr    = bsums + 1024;          // E
    int* inv   = lr + E;                // E
    size_t iofs = (size_t)(N + 1) + N + 1024 + 2 * (size_t)E;
    iofs = (iofs + 3) & ~(size_t)3;     // 16B align
    float2* pe = (float2*)((int*)d_ws + iofs);          // E
    ushort_t* B = (ushort_t*)(pe + E);                  // ht  bf16 [N,64]
    ushort_t* D = B + (size_t)N * 64;                   // h/t bf16 [N,64]
    float* nrm  = (float*)(D + (size_t)N * 64);         // ||h|| fp32 [N]
    float* hbs  = nrm + N;              // 3*64
    float* hbns = hbs + 192;            // 3 (+1 pad)
    ushort_t* Bpk1 = (ushort_t*)(hbns + 4);             // 8192
    ushort_t* Bpk2 = Bpk1 + 8192;                       // 4096
    ushort_t* Bpk3 = Bpk2 + 4096;                       // 4096

    dim3 blk(256);
    int nodeBlocks = (N + 3) / 4;
    int gemmBlocks = (N + 63) / 64;
    int edgeThBlocks = (E + 255) / 256;
    int nb = (N + SCAN_B - 1) / SCAN_B;

    // prep: bias orbits + W packs + CSR (rank -> scan -> build -> gather)
    k_bias<<<1, 192, 0, stream>>>(b1, b2, b3, hbs, hbns);
    k_wcvt<<<32, blk, 0, stream>>>(W1, 128, Bpk1);
    k_wcvt<<<16, blk, 0, stream>>>(W2, 64, Bpk2);
    k_wcvt<<<16, blk, 0, stream>>>(W3, 64, Bpk3);
    hipMemsetAsync(cnt, 0, (size_t)N * sizeof(int), stream);
    k_rank<<<edgeThBlocks, blk, 0, stream>>>(dst, cnt, lr, E);
    k_scan1<<<nb, blk, 0, stream>>>(cnt, off, bsums, N);
    k_scan2<<<1, blk, 0, stream>>>(bsums, nb, off, N);
    k_scan3<<<(N + 255) / 256, blk, 0, stream>>>(off, bsums, N);
    k_build<<<edgeThBlocks, blk, 0, stream>>>(dst, off, lr, inv, E);
    k_gather<<<edgeThBlocks, blk, 0, stream>>>(src, adj, inv, pe, E);

    // layer 1
    k_gemm1<<<gemmBlocks, blk, 0, stream>>>(x, Bpk1, hbs, hbns, B, N);
    k_agg_act<false><<<nodeBlocks, blk, 0, stream>>>(B, off, pe, D, nrm, N);
    // layer 2
    k_gemm64<<<gemmBlocks, blk, 0, stream>>>(D, nrm, Bpk2, hbs + 64, hbns + 1, B, N);
    k_agg_act<false><<<nodeBlocks, blk, 0, stream>>>(B, off, pe, D, nrm, N);
    // layer 3
    k_gemm64<<<gemmBlocks, blk, 0, stream>>>(D, nrm, Bpk3, hbs + 128, hbns + 2, B, N);
    k_agg_act<true><<<nodeBlocks, blk, 0, stream>>>(B, off, pe, D, nullptr, N);

    // head
    k_head<<<nodeBlocks, blk, 0, stream>>>(D, W4, b4, W5, b5, out, N);
}

// Round 6
// 419.123 us; speedup vs baseline: 4.1005x; 1.2464x over previous
//
#include <hip/hip_runtime.h>
#include <hip/hip_bf16.h>
#include <math.h>

#define NFEAT 128
#define NHID  64
#define SCAN_B 1024
#define ATH996 3.106303f   // artanh(0.996)

typedef __attribute__((ext_vector_type(8))) short short8;
typedef __attribute__((ext_vector_type(4))) float floatx4;
typedef unsigned short ushort_t;

__device__ __forceinline__ float wave_sum(float v) {
#pragma unroll
    for (int m = 1; m < 64; m <<= 1) v += __shfl_xor(v, m, 64);
    return v;
}

__device__ __forceinline__ float fast_tanh(float x) {
    float e = __expf(2.f * x);
    return 1.f - 2.f / (e + 1.f);
}

__device__ __forceinline__ float artanh_clip(float v) {
    const float lim = 0.99999988f;  // float(1 - 1e-7)
    v = fminf(fmaxf(v, -lim), lim);
    return 0.5f * __logf((1.f + v) / (1.f - v));
}

__device__ __forceinline__ unsigned pack2(float a, float b) {
    __hip_bfloat16 x = __float2bfloat16(a), y = __float2bfloat16(b);
    ushort_t ux = *(ushort_t*)&x, uy = *(ushort_t*)&y;
    return (unsigned)ux | ((unsigned)uy << 16);
}

__device__ __forceinline__ float bf2f(ushort_t u) {
    return __uint_as_float(((unsigned)u) << 16);
}
__device__ __forceinline__ ushort_t f2bf(float f) {
    __hip_bfloat16 h = __float2bfloat16(f);
    return *(ushort_t*)&h;
}

// ---- CSR build --------------------------------------------------------------

__global__ __launch_bounds__(256) void k_rank(const int* __restrict__ dst,
        int* __restrict__ cnt, int* __restrict__ lr, int e) {
    int i = blockIdx.x * 256 + threadIdx.x;
    if (i < e) lr[i] = atomicAdd(&cnt[dst[i]], 1);
}

__global__ __launch_bounds__(256) void k_scan1(const int* __restrict__ cnt,
        int* __restrict__ off, int* __restrict__ bsums, int n) {
    __shared__ int s[256];
    int tid = threadIdx.x;
    int base = blockIdx.x * SCAN_B + tid * 4;
    int c0 = 0, c1 = 0, c2 = 0, c3 = 0;
    if (base + 0 < n) c0 = cnt[base + 0];
    if (base + 1 < n) c1 = cnt[base + 1];
    if (base + 2 < n) c2 = cnt[base + 2];
    if (base + 3 < n) c3 = cnt[base + 3];
    int tsum = c0 + c1 + c2 + c3;
    s[tid] = tsum; __syncthreads();
    for (int o = 1; o < 256; o <<= 1) {
        int v = (tid >= o) ? s[tid - o] : 0;
        __syncthreads();
        s[tid] += v;
        __syncthreads();
    }
    int excl = s[tid] - tsum;
    if (base + 0 < n) off[base + 0] = excl;
    if (base + 1 < n) off[base + 1] = excl + c0;
    if (base + 2 < n) off[base + 2] = excl + c0 + c1;
    if (base + 3 < n) off[base + 3] = excl + c0 + c1 + c2;
    if (tid == 255) bsums[blockIdx.x] = s[255];
}

__global__ __launch_bounds__(256) void k_scan2(int* __restrict__ bsums, int nb,
                                               int* __restrict__ off, int ntot) {
    __shared__ int s[256];
    int tid = threadIdx.x;
    int base = tid * 4;
    int c0 = 0, c1 = 0, c2 = 0, c3 = 0;
    if (base + 0 < nb) c0 = bsums[base + 0];
    if (base + 1 < nb) c1 = bsums[base + 1];
    if (base + 2 < nb) c2 = bsums[base + 2];
    if (base + 3 < nb) c3 = bsums[base + 3];
    int tsum = c0 + c1 + c2 + c3;
    s[tid] = tsum; __syncthreads();
    for (int o = 1; o < 256; o <<= 1) {
        int v = (tid >= o) ? s[tid - o] : 0;
        __syncthreads();
        s[tid] += v;
        __syncthreads();
    }
    int excl = s[tid] - tsum;
    if (base + 0 < nb) bsums[base + 0] = excl;
    if (base + 1 < nb) bsums[base + 1] = excl + c0;
    if (base + 2 < nb) bsums[base + 2] = excl + c0 + c1;
    if (base + 3 < nb) bsums[base + 3] = excl + c0 + c1 + c2;
    if (tid == 255) off[ntot] = s[255];
}

__global__ __launch_bounds__(256) void k_scan3(int* __restrict__ off,
        const int* __restrict__ bsums, int n) {
    int i = blockIdx.x * 256 + threadIdx.x;
    if (i < n) off[i] += bsums[i >> 10];
}

__global__ __launch_bounds__(256) void k_build(const int* __restrict__ dst,
        const int* __restrict__ off, const int* __restrict__ lr,
        int* __restrict__ inv, int e) {
    int i = blockIdx.x * 256 + threadIdx.x;
    if (i < e) inv[off[dst[i]] + lr[i]] = i;
}

__global__ __launch_bounds__(256) void k_gather(const int* __restrict__ src,
        const float* __restrict__ adj, const int* __restrict__ inv,
        float2* __restrict__ pe, int e) {
    int p = blockIdx.x * 256 + threadIdx.x;
    if (p < e) {
        int i = inv[p];
        pe[p] = make_float2(__int_as_float(src[i]), adj[i]);
    }
}

// hyperbolic bias per layer
__global__ __launch_bounds__(192) void k_bias(const float* __restrict__ b1,
        const float* __restrict__ b2, const float* __restrict__ b3,
        float* __restrict__ hbs, float* __restrict__ hbns) {
    int wv = threadIdx.x >> 6, lane = threadIdx.x & 63;
    const float* b = (wv == 0) ? b1 : (wv == 1) ? b2 : b3;
    float bv = b[lane];
    float bn = fmaxf(sqrtf(wave_sum(bv * bv)), 1e-15f);
    float th = fast_tanh(bn);
    float f = th / bn;
    float hn = th;
    if (th > 0.996f) { f = 0.996f / bn; hn = 0.996f; }
    hbs[wv * 64 + lane] = bv * f;
    if (lane == 0) hbns[wv] = hn;
}

// pack W [64 out, K in] into MFMA B-fragment order (bf16), 4 nf
__global__ __launch_bounds__(256) void k_wcvt(const float* __restrict__ W, int K,
                                              ushort_t* __restrict__ Bpk) {
    int tot = 64 * K;
    for (int o = blockIdx.x * 256 + threadIdx.x; o < tot; o += gridDim.x * 256) {
        int j = o & 7, c = (o >> 3) & 15, nf = (o >> 7) & 3, hi = (o >> 9) & 3,
            ks = o >> 11;
        int k = ks * 32 + hi * 8 + j;
        int col = nf * 16 + c;
        Bpk[o] = f2bf(W[col * K + k]);
    }
}

// pack W4 [32,64]: 2 nf, KS=2
__global__ __launch_bounds__(256) void k_wcvt4(const float* __restrict__ W,
                                               ushort_t* __restrict__ Bpk) {
    int o = blockIdx.x * 256 + threadIdx.x;
    if (o < 2048) {
        int j = o & 7, c = (o >> 3) & 15, nf = (o >> 7) & 1, hi = (o >> 8) & 3,
            ks = o >> 10;
        Bpk[o] = f2bf(W[(nf * 16 + c) * 64 + ks * 32 + hi * 8 + j]);
    }
}

// pack W5 [16,32]: 1 nf, KS=1
__global__ __launch_bounds__(256) void k_wcvt5(const float* __restrict__ W,
                                               ushort_t* __restrict__ Bpk) {
    int o = blockIdx.x * 256 + threadIdx.x;
    if (o < 512) {
        int j = o & 7, c = (o >> 3) & 15, hi = o >> 7;
        Bpk[o] = f2bf(W[c * 32 + hi * 8 + j]);
    }
}

// epilogue transform: HypLinear tail collapsed analytically (16-lane groups)
__device__ __forceinline__ void epi_row(const floatx4* acc, int r, float pn,
        float hbn, const float* __restrict__ hb, int c, float outv[4]) {
    float pp = 0.f;
#pragma unroll
    for (int nf = 0; nf < 4; ++nf) pp += acc[nf][r] * acc[nf][r];
#pragma unroll
    for (int m = 1; m < 16; m <<= 1) pp += __shfl_xor(pp, m, 64);
    float mpn = sqrtf(pp);
    float an = artanh_clip(pn);
    if (hbn <= 1e-15f) {
        float targ = (mpn / pn) * an;
        float scale = (targ > ATH996) ? (ATH996 / mpn) : (an / pn);
        if (mpn <= 1e-15f) scale = 0.f;
#pragma unroll
        for (int nf = 0; nf < 4; ++nf) outv[nf] = acc[nf][r] * scale;
    } else {
        float targ = (mpn / pn) * an;
        float th = fast_tanh(targ);
        float rn = fminf(th, 0.996f);
        float rs = (mpn <= 1e-15f) ? 0.f : (rn / mpn);
        float res[4], xyp = 0.f;
#pragma unroll
        for (int nf = 0; nf < 4; ++nf) {
            res[nf] = acc[nf][r] * rs;
            xyp += res[nf] * hb[nf * 16 + c];
        }
#pragma unroll
        for (int m = 1; m < 16; m <<= 1) xyp += __shfl_xor(xyp, m, 64);
        float x2 = rn * rn, y2 = hbn * hbn;
        float den = fmaxf(1.f + 2.f * xyp + x2 * y2, 1e-15f);
        float ca = (1.f + 2.f * xyp + y2) / den, cb = (1.f - x2) / den;
        float mv[4], mm = 0.f;
#pragma unroll
        for (int nf = 0; nf < 4; ++nf) {
            mv[nf] = ca * res[nf] + cb * hb[nf * 16 + c];
            mm += mv[nf] * mv[nf];
        }
#pragma unroll
        for (int m = 1; m < 16; m <<= 1) mm += __shfl_xor(mm, m, 64);
        float mn = sqrtf(mm);
        float mc = fminf(fmaxf(mn, 1e-15f), 0.996f);
        float msc = ((mn > 0.996f) ? (0.996f / mn) : 1.f) * artanh_clip(mc) / mc;
#pragma unroll
        for (int nf = 0; nf < 4; ++nf) outv[nf] = mv[nf] * msc;
    }
}

// layer 1 GEMM: x fp32 [N,128] -> (expmap0+proj fused) -> MFMA -> tail -> ht bf16
__global__ __launch_bounds__(256) void k_gemm1(
        const float* __restrict__ x, const ushort_t* __restrict__ Bpk,
        const float* __restrict__ hb, const float* __restrict__ hbn_p,
        ushort_t* __restrict__ htout, int n) {
    constexpr int RB = 256;
    __shared__ __align__(16) unsigned char As[64 * RB];
    __shared__ float pns[64];
    int tid = threadIdx.x, wv = tid >> 6, lane = tid & 63;
    int rowBase = blockIdx.x * 64;
#pragma unroll
    for (int it = 0; it < 16; ++it) {
        int row = wv * 16 + it, rg = rowBase + row;
        float2 v = make_float2(0.f, 0.f);
        if (rg < n) v = *(const float2*)(x + (size_t)rg * NFEAT + lane * 2);
        float ss = wave_sum(v.x * v.x + v.y * v.y);
        float nr = fmaxf(sqrtf(ss), 1e-15f);
        float th = fast_tanh(nr);
        float f = th / nr;
        float pn = fmaxf(th, 1e-15f);
        if (th > 0.996f) { f = 0.996f / nr; pn = 0.996f; }
        unsigned byte = (unsigned)(row * RB + lane * 4) ^ ((row & 7) << 4);
        *(unsigned*)(As + byte) = pack2(v.x * f, v.y * f);
        if (lane == 0) pns[row] = pn;
    }
    int hi = lane >> 4, c = lane & 15;
    short8 bf[4][4];
#pragma unroll
    for (int ks = 0; ks < 4; ++ks)
#pragma unroll
        for (int nf = 0; nf < 4; ++nf)
            bf[ks][nf] = *(const short8*)(Bpk + (((size_t)(ks * 4 + hi) * 4 + nf) * 16 + c) * 8);
    floatx4 acc[4];
#pragma unroll
    for (int nf = 0; nf < 4; ++nf)
#pragma unroll
        for (int r = 0; r < 4; ++r) acc[nf][r] = 0.f;
    int arow = wv * 16 + c;
#pragma unroll
    for (int ks = 0; ks < 4; ++ks) {
        unsigned byte = (unsigned)(arow * RB + ks * 64 + hi * 16) ^ ((arow & 7) << 4);
        short8 af = *(const short8*)(As + byte);
#pragma unroll
        for (int nf = 0; nf < 4; ++nf)
            acc[nf] = __builtin_amdgcn_mfma_f32_16x16x32_bf16(af, bf[ks][nf], acc[nf], 0, 0, 0);
    }
    float hbn = hbn_p[0];
#pragma unroll
    for (int r = 0; r < 4; ++r) {
        int row = wv * 16 + hi * 4 + r, rg = rowBase + row;
        float outv[4];
        epi_row(acc, r, pns[row], hbn, hb, c, outv);
        if (rg < n) {
#pragma unroll
            for (int nf = 0; nf < 4; ++nf)
                htout[(size_t)rg * 64 + nf * 16 + c] = f2bf(outv[nf]);
        }
    }
}

// layers 2/3 GEMM
__global__ __launch_bounds__(256) void k_gemm64(
        const ushort_t* __restrict__ h, const float* __restrict__ nrm_in,
        const ushort_t* __restrict__ Bpk, const float* __restrict__ hb,
        const float* __restrict__ hbn_p, ushort_t* __restrict__ htout, int n) {
    constexpr int RB = 128;
    __shared__ __align__(16) unsigned char As[64 * RB];
    int tid = threadIdx.x, wv = tid >> 6, lane = tid & 63;
    int rowBase = blockIdx.x * 64;
#pragma unroll
    for (int it = 0; it < 8; ++it) {
        int row = wv * 16 + it * 2 + (lane >> 5), rg = rowBase + row;
        int cl = lane & 31;
        unsigned pk = 0;
        if (rg < n) pk = *(const unsigned*)(h + (size_t)rg * 64 + cl * 2);
        unsigned byte = (unsigned)(row * RB + cl * 4) ^ ((row & 7) << 4);
        *(unsigned*)(As + byte) = pk;
    }
    int hi = lane >> 4, c = lane & 15;
    short8 bf[2][4];
#pragma unroll
    for (int ks = 0; ks < 2; ++ks)
#pragma unroll
        for (int nf = 0; nf < 4; ++nf)
            bf[ks][nf] = *(const short8*)(Bpk + (((size_t)(ks * 4 + hi) * 4 + nf) * 16 + c) * 8);
    floatx4 acc[4];
#pragma unroll
    for (int nf = 0; nf < 4; ++nf)
#pragma unroll
        for (int r = 0; r < 4; ++r) acc[nf][r] = 0.f;
    int arow = wv * 16 + c;
#pragma unroll
    for (int ks = 0; ks < 2; ++ks) {
        unsigned byte = (unsigned)(arow * RB + ks * 64 + hi * 16) ^ ((arow & 7) << 4);
        short8 af = *(const short8*)(As + byte);
#pragma unroll
        for (int nf = 0; nf < 4; ++nf)
            acc[nf] = __builtin_amdgcn_mfma_f32_16x16x32_bf16(af, bf[ks][nf], acc[nf], 0, 0, 0);
    }
    float hbn = hbn_p[0];
#pragma unroll
    for (int r = 0; r < 4; ++r) {
        int row = wv * 16 + hi * 4 + r, rg = rowBase + row;
        float pn = (rg < n) ? nrm_in[rg] : 1e-15f;
        float outv[4];
        epi_row(acc, r, pn, hbn, hb, c, outv);
        if (rg < n) {
#pragma unroll
            for (int nf = 0; nf < 4; ++nf)
                htout[(size_t)rg * 64 + nf * 16 + c] = f2bf(outv[nf]);
        }
    }
}

// CSR aggregation (bf16 gathers, 4-deep unroll) + HypAct
template <bool TANGENT_OUT>
__global__ __launch_bounds__(256) void k_agg_act(
        const ushort_t* __restrict__ ht, const int* __restrict__ off,
        const float2* __restrict__ pe, ushort_t* __restrict__ hout,
        float* __restrict__ nrm_out, int n) {
    int wv = threadIdx.x >> 6, lane = threadIdx.x & 63;
    int node = blockIdx.x * 4 + wv;
    if (node >= n) return;
    node = __builtin_amdgcn_readfirstlane(node);
    int beg = off[node], end = off[node + 1];
    float a0 = 0.f, a1 = 0.f, a2 = 0.f, a3 = 0.f;
    int e = beg;
    for (; e + 3 < end; e += 4) {
        float2 p0 = pe[e], p1 = pe[e + 1], p2 = pe[e + 2], p3 = pe[e + 3];
        a0 = fmaf(p0.y, bf2f(ht[(size_t)__float_as_int(p0.x) * 64 + lane]), a0);
        a1 = fmaf(p1.y, bf2f(ht[(size_t)__float_as_int(p1.x) * 64 + lane]), a1);
        a2 = fmaf(p2.y, bf2f(ht[(size_t)__float_as_int(p2.x) * 64 + lane]), a2);
        a3 = fmaf(p3.y, bf2f(ht[(size_t)__float_as_int(p3.x) * 64 + lane]), a3);
    }
    for (; e < end; ++e) {
        float2 p0 = pe[e];
        a0 = fmaf(p0.y, bf2f(ht[(size_t)__float_as_int(p0.x) * 64 + lane]), a0);
    }
    float acc = (a0 + a1) + (a2 + a3);
    float un = fmaxf(sqrtf(wave_sum(acc * acc)), 1e-15f);
    float thu = fast_tanh(un);
    float pf = thu / un, pn = thu;
    if (thu > 0.996f) { pf = 0.996f / un; pn = 0.996f; }
    float pnc = fmaxf(pn, 1e-15f);
    float t = artanh_clip(pnc) / pnc * pf * acc;   // logmap0(proj(expmap0(acc)))
    t = fmaxf(t, 0.f);                              // relu
    float tn = fmaxf(sqrtf(wave_sum(t * t)), 1e-15f);
    if (TANGENT_OUT) {
        float o = (tn > ATH996) ? (ATH996 / tn) * t : t;
        hout[(size_t)node * 64 + lane] = f2bf(o);
    } else {
        float tht = fast_tanh(tn);
        float rf = tht / tn, rn = tht;
        if (tht > 0.996f) { rf = 0.996f / tn; rn = 0.996f; }
        hout[(size_t)node * 64 + lane] = f2bf(rf * t);
        if (lane == 0) nrm_out[node] = fmaxf(rn, 1e-15f);
    }
}

// MFMA head: z = relu(t@W4.T+b4); out = log_softmax(z@W5.T+b5)
// 64-node tiles, per-wave self-contained (no barriers)
__global__ __launch_bounds__(256) void k_head(
        const ushort_t* __restrict__ t_in, const ushort_t* __restrict__ Bpk4,
        const float* __restrict__ b4, const ushort_t* __restrict__ Bpk5,
        const float* __restrict__ b5, float* __restrict__ out, int n) {
    constexpr int RB = 128;
    __shared__ __align__(16) unsigned char As[64 * RB];
    __shared__ __align__(16) unsigned char Zs[4][16 * 80];  // 80B rows: 2-way max
    int tid = threadIdx.x, wv = tid >> 6, lane = tid & 63;
    int rowBase = blockIdx.x * 64;
    // stage t rows (bf16)
#pragma unroll
    for (int it = 0; it < 8; ++it) {
        int row = wv * 16 + it * 2 + (lane >> 5), rg = rowBase + row;
        int cl = lane & 31;
        unsigned pk = 0;
        if (rg < n) pk = *(const unsigned*)(t_in + (size_t)rg * 64 + cl * 2);
        unsigned byte = (unsigned)(row * RB + cl * 4) ^ ((row & 7) << 4);
        *(unsigned*)(As + byte) = pk;
    }
    int hi = lane >> 4, c = lane & 15;
    // GEMM A: t @ W4^T  (2 ks x 2 nf)
    short8 bf4[2][2];
#pragma unroll
    for (int ks = 0; ks < 2; ++ks)
#pragma unroll
        for (int nf = 0; nf < 2; ++nf)
            bf4[ks][nf] = *(const short8*)(Bpk4 + (((size_t)(ks * 4 + hi) * 2 + nf) * 16 + c) * 8);
    floatx4 acc[2];
#pragma unroll
    for (int nf = 0; nf < 2; ++nf)
#pragma unroll
        for (int r = 0; r < 4; ++r) acc[nf][r] = 0.f;
    int arow = wv * 16 + c;
#pragma unroll
    for (int ks = 0; ks < 2; ++ks) {
        unsigned byte = (unsigned)(arow * RB + ks * 64 + hi * 16) ^ ((arow & 7) << 4);
        short8 af = *(const short8*)(As + byte);
#pragma unroll
        for (int nf = 0; nf < 2; ++nf)
            acc[nf] = __builtin_amdgcn_mfma_f32_16x16x32_bf16(af, bf4[ks][nf], acc[nf], 0, 0, 0);
    }
    // z = relu(acc + b4) -> Zs (bf16, row stride 80B)
    float bb0 = b4[c], bb1 = b4[16 + c];
#pragma unroll
    for (int r = 0; r < 4; ++r) {
        int zr = hi * 4 + r;
        *(ushort_t*)(Zs[wv] + zr * 80 + c * 2) = f2bf(fmaxf(acc[0][r] + bb0, 0.f));
        *(ushort_t*)(Zs[wv] + zr * 80 + (16 + c) * 2) = f2bf(fmaxf(acc[1][r] + bb1, 0.f));
    }
    // GEMM B: z @ W5^T  (1 ks x 1 nf)
    short8 bf5 = *(const short8*)(Bpk5 + ((size_t)(hi * 16 + c)) * 8);
    short8 zf = *(const short8*)(Zs[wv] + c * 80 + hi * 16);
    floatx4 acc5;
#pragma unroll
    for (int r = 0; r < 4; ++r) acc5[r] = 0.f;
    acc5 = __builtin_amdgcn_mfma_f32_16x16x32_bf16(zf, bf5, acc5, 0, 0, 0);
    // log_softmax per row (16-lane groups hold the 16 classes)
    float b5v = b5[c];
#pragma unroll
    for (int r = 0; r < 4; ++r) {
        float y = acc5[r] + b5v;
        float mx = y;
#pragma unroll
        for (int mk = 1; mk < 16; mk <<= 1) mx = fmaxf(mx, __shfl_xor(mx, mk, 64));
        float sm = __expf(y - mx);
#pragma unroll
        for (int mk = 1; mk < 16; mk <<= 1) sm += __shfl_xor(sm, mk, 64);
        int rg = rowBase + wv * 16 + hi * 4 + r;
        if (rg < n) out[(size_t)rg * 16 + c] = y - mx - __logf(sm);
    }
}

extern "C" void kernel_launch(void* const* d_in, const int* in_sizes, int n_in,
                              void* d_out, int out_size, void* d_ws, size_t ws_size,
                              hipStream_t stream) {
    const float* x   = (const float*)d_in[0];
    const int*   src = (const int*)d_in[1];
    const int*   dst = (const int*)d_in[2];
    const float* adj = (const float*)d_in[3];
    const float* W1  = (const float*)d_in[4];  const float* b1 = (const float*)d_in[5];
    const float* W2  = (const float*)d_in[6];  const float* b2 = (const float*)d_in[7];
    const float* W3  = (const float*)d_in[8];  const float* b3 = (const float*)d_in[9];
    const float* W4  = (const float*)d_in[10]; const float* b4 = (const float*)d_in[11];
    const float* W5  = (const float*)d_in[12]; const float* b5 = (const float*)d_in[13];
    float* out = (float*)d_out;

    const int N = in_sizes[0] / NFEAT;
    const int E = in_sizes[1];

    // ws layout
    int* off   = (int*)d_ws;            // N+1
    int* cnt   = off + (N + 1);         // N
    int* bsums = cnt + N;               // 1024
    int* lr    = bsums + 1024;          // E
    int* inv   = lr + E;                // E
    size_t iofs = (size_t)(N + 1) + N + 1024 + 2 * (size_t)E;
    iofs = (iofs + 3) & ~(size_t)3;     // 16B align
    float2* pe = (float2*)((int*)d_ws + iofs);          // E
    ushort_t* B = (ushort_t*)(pe + E);                  // ht  bf16 [N,64]
    ushort_t* D = B + (size_t)N * 64;                   // h/t bf16 [N,64]
    float* nrm  = (float*)(D + (size_t)N * 64);         // ||h|| fp32 [N]
    float* hbs  = nrm + N;              // 3*64
    float* hbns = hbs + 192;            // 3 (+1 pad)
    ushort_t* Bpk1 = (ushort_t*)(hbns + 4);             // 8192
    ushort_t* Bpk2 = Bpk1 + 8192;                       // 4096
    ushort_t* Bpk3 = Bpk2 + 4096;                       // 4096
    ushort_t* Bpk4 = Bpk3 + 4096;                       // 2048
    ushort_t* Bpk5 = Bpk4 + 2048;                       // 512

    dim3 blk(256);
    int nodeBlocks = (N + 3) / 4;
    int gemmBlocks = (N + 63) / 64;
    int edgeThBlocks = (E + 255) / 256;
    int nb = (N + SCAN_B - 1) / SCAN_B;

    // prep: bias orbits + W packs + CSR
    k_bias<<<1, 192, 0, stream>>>(b1, b2, b3, hbs, hbns);
    k_wcvt<<<32, blk, 0, stream>>>(W1, 128, Bpk1);
    k_wcvt<<<16, blk, 0, stream>>>(W2, 64, Bpk2);
    k_wcvt<<<16, blk, 0, stream>>>(W3, 64, Bpk3);
    k_wcvt4<<<8, blk, 0, stream>>>(W4, Bpk4);
    k_wcvt5<<<2, blk, 0, stream>>>(W5, Bpk5);
    hipMemsetAsync(cnt, 0, (size_t)N * sizeof(int), stream);
    k_rank<<<edgeThBlocks, blk, 0, stream>>>(dst, cnt, lr, E);
    k_scan1<<<nb, blk, 0, stream>>>(cnt, off, bsums, N);
    k_scan2<<<1, blk, 0, stream>>>(bsums, nb, off, N);
    k_scan3<<<(N + 255) / 256, blk, 0, stream>>>(off, bsums, N);
    k_build<<<edgeThBlocks, blk, 0, stream>>>(dst, off, lr, inv, E);
    k_gather<<<edgeThBlocks, blk, 0, stream>>>(src, adj, inv, pe, E);

    // layer 1
    k_gemm1<<<gemmBlocks, blk, 0, stream>>>(x, Bpk1, hbs, hbns, B, N);
    k_agg_act<false><<<nodeBlocks, blk, 0, stream>>>(B, off, pe, D, nrm, N);
    // layer 2
    k_gemm64<<<gemmBlocks, blk, 0, stream>>>(D, nrm, Bpk2, hbs + 64, hbns + 1, B, N);
    k_agg_act<false><<<nodeBlocks, blk, 0, stream>>>(B, off, pe, D, nrm, N);
    // layer 3
    k_gemm64<<<gemmBlocks, blk, 0, stream>>>(D, nrm, Bpk3, hbs + 128, hbns + 2, B, N);
    k_agg_act<true><<<nodeBlocks, blk, 0, stream>>>(B, off, pe, D, nullptr, N);

    // head (MFMA)
    k_head<<<gemmBlocks, blk, 0, stream>>>(D, Bpk4, b4, Bpk5, b5, out, N);
}

// Round 7
// 359.855 us; speedup vs baseline: 4.7758x; 1.1647x over previous
//
#include <hip/hip_runtime.h>
#include <hip/hip_bf16.h>
#include <hip/hip_fp16.h>
#include <math.h>

#define NFEAT 128
#define NHID  64
#define SCAN_B 1024
#define ATH996 3.106303f   // artanh(0.996)

typedef __attribute__((ext_vector_type(8))) short short8;
typedef __attribute__((ext_vector_type(4))) float floatx4;
typedef unsigned short ushort_t;

__device__ __forceinline__ float wave_sum(float v) {
#pragma unroll
    for (int m = 1; m < 64; m <<= 1) v += __shfl_xor(v, m, 64);
    return v;
}

__device__ __forceinline__ float fast_tanh(float x) {
    float e = __expf(2.f * x);
    return 1.f - 2.f / (e + 1.f);
}

__device__ __forceinline__ float artanh_clip(float v) {
    const float lim = 0.99999988f;  // float(1 - 1e-7)
    v = fminf(fmaxf(v, -lim), lim);
    return 0.5f * __logf((1.f + v) / (1.f - v));
}

__device__ __forceinline__ unsigned pack2(float a, float b) {
    __hip_bfloat16 x = __float2bfloat16(a), y = __float2bfloat16(b);
    ushort_t ux = *(ushort_t*)&x, uy = *(ushort_t*)&y;
    return (unsigned)ux | ((unsigned)uy << 16);
}

__device__ __forceinline__ float bf2f(ushort_t u) {
    return __uint_as_float(((unsigned)u) << 16);
}
__device__ __forceinline__ ushort_t f2bf(float f) {
    __hip_bfloat16 h = __float2bfloat16(f);
    return *(ushort_t*)&h;
}

// packed edge: bits[31:15] = src (17b), bits[14:0] = fp16(adj) sans sign
__device__ __forceinline__ float pe_adj(unsigned p) {
    return __half2float(__ushort_as_half((ushort_t)(p & 0x7fffu)));
}

// ---- CSR build --------------------------------------------------------------

__global__ __launch_bounds__(256) void k_rank(const int* __restrict__ dst,
        int* __restrict__ cnt, int* __restrict__ lr, int e) {
    int i = blockIdx.x * 256 + threadIdx.x;
    if (i < e) lr[i] = atomicAdd(&cnt[dst[i]], 1);
}

__global__ __launch_bounds__(256) void k_scan1(const int* __restrict__ cnt,
        int* __restrict__ off, int* __restrict__ bsums, int n) {
    __shared__ int s[256];
    int tid = threadIdx.x;
    int base = blockIdx.x * SCAN_B + tid * 4;
    int c0 = 0, c1 = 0, c2 = 0, c3 = 0;
    if (base + 0 < n) c0 = cnt[base + 0];
    if (base + 1 < n) c1 = cnt[base + 1];
    if (base + 2 < n) c2 = cnt[base + 2];
    if (base + 3 < n) c3 = cnt[base + 3];
    int tsum = c0 + c1 + c2 + c3;
    s[tid] = tsum; __syncthreads();
    for (int o = 1; o < 256; o <<= 1) {
        int v = (tid >= o) ? s[tid - o] : 0;
        __syncthreads();
        s[tid] += v;
        __syncthreads();
    }
    int excl = s[tid] - tsum;
    if (base + 0 < n) off[base + 0] = excl;
    if (base + 1 < n) off[base + 1] = excl + c0;
    if (base + 2 < n) off[base + 2] = excl + c0 + c1;
    if (base + 3 < n) off[base + 3] = excl + c0 + c1 + c2;
    if (tid == 255) bsums[blockIdx.x] = s[255];
}

__global__ __launch_bounds__(256) void k_scan2(int* __restrict__ bsums, int nb,
                                               int* __restrict__ off, int ntot) {
    __shared__ int s[256];
    int tid = threadIdx.x;
    int base = tid * 4;
    int c0 = 0, c1 = 0, c2 = 0, c3 = 0;
    if (base + 0 < nb) c0 = bsums[base + 0];
    if (base + 1 < nb) c1 = bsums[base + 1];
    if (base + 2 < nb) c2 = bsums[base + 2];
    if (base + 3 < nb) c3 = bsums[base + 3];
    int tsum = c0 + c1 + c2 + c3;
    s[tid] = tsum; __syncthreads();
    for (int o = 1; o < 256; o <<= 1) {
        int v = (tid >= o) ? s[tid - o] : 0;
        __syncthreads();
        s[tid] += v;
        __syncthreads();
    }
    int excl = s[tid] - tsum;
    if (base + 0 < nb) bsums[base + 0] = excl;
    if (base + 1 < nb) bsums[base + 1] = excl + c0;
    if (base + 2 < nb) bsums[base + 2] = excl + c0 + c1;
    if (base + 3 < nb) bsums[base + 3] = excl + c0 + c1 + c2;
    if (tid == 255) off[ntot] = s[255];
}

__global__ __launch_bounds__(256) void k_scan3(int* __restrict__ off,
        const int* __restrict__ bsums, int n) {
    int i = blockIdx.x * 256 + threadIdx.x;
    if (i < n) off[i] += bsums[i >> 10];
}

// fused build+gather: scatter packed (src|fp16 adj) directly to final slot
__global__ __launch_bounds__(256) void k_build(const int* __restrict__ dst,
        const int* __restrict__ src, const float* __restrict__ adj,
        const int* __restrict__ off, const int* __restrict__ lr,
        unsigned* __restrict__ pe, int e) {
    int i = blockIdx.x * 256 + threadIdx.x;
    if (i < e) {
        int pos = off[dst[i]] + lr[i];
        unsigned ab = (unsigned)__half_as_ushort(__float2half(adj[i])) & 0x7fffu;
        pe[pos] = ((unsigned)src[i] << 15) | ab;
    }
}

// ---- one-shot prep: all weight packs + hyperbolic biases --------------------
// blocks 0-31: W1(8192) | 32-47: W2(4096) | 48-63: W3(4096)
// 64-71: W4(2048) | 72-73: W5(512) | 74: biases
__global__ __launch_bounds__(256) void k_prep(
        const float* __restrict__ W1, const float* __restrict__ W2,
        const float* __restrict__ W3, const float* __restrict__ W4,
        const float* __restrict__ W5, const float* __restrict__ b1,
        const float* __restrict__ b2, const float* __restrict__ b3,
        ushort_t* __restrict__ Bpk1, ushort_t* __restrict__ Bpk2,
        ushort_t* __restrict__ Bpk3, ushort_t* __restrict__ Bpk4,
        ushort_t* __restrict__ Bpk5, float* __restrict__ hbs,
        float* __restrict__ hbns) {
    int bid = blockIdx.x, tid = threadIdx.x;
    if (bid < 64) {
        // 64-out packs: W1 (K=128) or W2/W3 (K=64)
        const float* W; ushort_t* Bpk; int K, o;
        if (bid < 32)      { W = W1; Bpk = Bpk1; K = 128; o = bid * 256 + tid; }
        else if (bid < 48) { W = W2; Bpk = Bpk2; K = 64;  o = (bid - 32) * 256 + tid; }
        else               { W = W3; Bpk = Bpk3; K = 64;  o = (bid - 48) * 256 + tid; }
        int j = o & 7, c = (o >> 3) & 15, nf = (o >> 7) & 3, hi = (o >> 9) & 3,
            ks = o >> 11;
        Bpk[o] = f2bf(W[(nf * 16 + c) * K + ks * 32 + hi * 8 + j]);
    } else if (bid < 72) {
        int o = (bid - 64) * 256 + tid;
        int j = o & 7, c = (o >> 3) & 15, nf = (o >> 7) & 1, hi = (o >> 8) & 3,
            ks = o >> 10;
        Bpk4[o] = f2bf(W4[(nf * 16 + c) * 64 + ks * 32 + hi * 8 + j]);
    } else if (bid < 74) {
        int o = (bid - 72) * 256 + tid;
        if (o < 512) {
            int j = o & 7, c = (o >> 3) & 15, hi = o >> 7;
            Bpk5[o] = f2bf(W5[c * 32 + hi * 8 + j]);
        }
    } else {
        if (tid < 192) {
            int wv = tid >> 6, lane = tid & 63;
            const float* b = (wv == 0) ? b1 : (wv == 1) ? b2 : b3;
            float bv = b[lane];
            float bn = fmaxf(sqrtf(wave_sum(bv * bv)), 1e-15f);
            float th = fast_tanh(bn);
            float f = th / bn;
            float hn = th;
            if (th > 0.996f) { f = 0.996f / bn; hn = 0.996f; }
            hbs[wv * 64 + lane] = bv * f;
            if (lane == 0) hbns[wv] = hn;
        }
    }
}

// epilogue transform: HypLinear tail collapsed analytically (16-lane groups)
__device__ __forceinline__ void epi_row(const floatx4* acc, int r, float pn,
        float hbn, const float* __restrict__ hb, int c, float outv[4]) {
    float pp = 0.f;
#pragma unroll
    for (int nf = 0; nf < 4; ++nf) pp += acc[nf][r] * acc[nf][r];
#pragma unroll
    for (int m = 1; m < 16; m <<= 1) pp += __shfl_xor(pp, m, 64);
    float mpn = sqrtf(pp);
    float an = artanh_clip(pn);
    if (hbn <= 1e-15f) {
        float targ = (mpn / pn) * an;
        float scale = (targ > ATH996) ? (ATH996 / mpn) : (an / pn);
        if (mpn <= 1e-15f) scale = 0.f;
#pragma unroll
        for (int nf = 0; nf < 4; ++nf) outv[nf] = acc[nf][r] * scale;
    } else {
        float targ = (mpn / pn) * an;
        float th = fast_tanh(targ);
        float rn = fminf(th, 0.996f);
        float rs = (mpn <= 1e-15f) ? 0.f : (rn / mpn);
        float res[4], xyp = 0.f;
#pragma unroll
        for (int nf = 0; nf < 4; ++nf) {
            res[nf] = acc[nf][r] * rs;
            xyp += res[nf] * hb[nf * 16 + c];
        }
#pragma unroll
        for (int m = 1; m < 16; m <<= 1) xyp += __shfl_xor(xyp, m, 64);
        float x2 = rn * rn, y2 = hbn * hbn;
        float den = fmaxf(1.f + 2.f * xyp + x2 * y2, 1e-15f);
        float ca = (1.f + 2.f * xyp + y2) / den, cb = (1.f - x2) / den;
        float mv[4], mm = 0.f;
#pragma unroll
        for (int nf = 0; nf < 4; ++nf) {
            mv[nf] = ca * res[nf] + cb * hb[nf * 16 + c];
            mm += mv[nf] * mv[nf];
        }
#pragma unroll
        for (int m = 1; m < 16; m <<= 1) mm += __shfl_xor(mm, m, 64);
        float mn = sqrtf(mm);
        float mc = fminf(fmaxf(mn, 1e-15f), 0.996f);
        float msc = ((mn > 0.996f) ? (0.996f / mn) : 1.f) * artanh_clip(mc) / mc;
#pragma unroll
        for (int nf = 0; nf < 4; ++nf) outv[nf] = mv[nf] * msc;
    }
}

// layer 1 GEMM: x fp32 [N,128] -> (expmap0+proj fused) -> MFMA -> tail -> ht bf16
__global__ __launch_bounds__(256) void k_gemm1(
        const float* __restrict__ x, const ushort_t* __restrict__ Bpk,
        const float* __restrict__ hb, const float* __restrict__ hbn_p,
        ushort_t* __restrict__ htout, int n) {
    constexpr int RB = 256;
    __shared__ __align__(16) unsigned char As[64 * RB];
    __shared__ float pns[64];
    int tid = threadIdx.x, wv = tid >> 6, lane = tid & 63;
    int rowBase = blockIdx.x * 64;
#pragma unroll
    for (int it = 0; it < 16; ++it) {
        int row = wv * 16 + it, rg = rowBase + row;
        float2 v = make_float2(0.f, 0.f);
        if (rg < n) v = *(const float2*)(x + (size_t)rg * NFEAT + lane * 2);
        float ss = wave_sum(v.x * v.x + v.y * v.y);
        float nr = fmaxf(sqrtf(ss), 1e-15f);
        float th = fast_tanh(nr);
        float f = th / nr;
        float pn = fmaxf(th, 1e-15f);
        if (th > 0.996f) { f = 0.996f / nr; pn = 0.996f; }
        unsigned byte = (unsigned)(row * RB + lane * 4) ^ ((row & 7) << 4);
        *(unsigned*)(As + byte) = pack2(v.x * f, v.y * f);
        if (lane == 0) pns[row] = pn;
    }
    int hi = lane >> 4, c = lane & 15;
    short8 bf[4][4];
#pragma unroll
    for (int ks = 0; ks < 4; ++ks)
#pragma unroll
        for (int nf = 0; nf < 4; ++nf)
            bf[ks][nf] = *(const short8*)(Bpk + (((size_t)(ks * 4 + hi) * 4 + nf) * 16 + c) * 8);
    floatx4 acc[4];
#pragma unroll
    for (int nf = 0; nf < 4; ++nf)
#pragma unroll
        for (int r = 0; r < 4; ++r) acc[nf][r] = 0.f;
    int arow = wv * 16 + c;
#pragma unroll
    for (int ks = 0; ks < 4; ++ks) {
        unsigned byte = (unsigned)(arow * RB + ks * 64 + hi * 16) ^ ((arow & 7) << 4);
        short8 af = *(const short8*)(As + byte);
#pragma unroll
        for (int nf = 0; nf < 4; ++nf)
            acc[nf] = __builtin_amdgcn_mfma_f32_16x16x32_bf16(af, bf[ks][nf], acc[nf], 0, 0, 0);
    }
    float hbn = hbn_p[0];
#pragma unroll
    for (int r = 0; r < 4; ++r) {
        int row = wv * 16 + hi * 4 + r, rg = rowBase + row;
        float outv[4];
        epi_row(acc, r, pns[row], hbn, hb, c, outv);
        if (rg < n) {
#pragma unroll
            for (int nf = 0; nf < 4; ++nf)
                htout[(size_t)rg * 64 + nf * 16 + c] = f2bf(outv[nf]);
        }
    }
}

// layers 2/3 GEMM
__global__ __launch_bounds__(256) void k_gemm64(
        const ushort_t* __restrict__ h, const float* __restrict__ nrm_in,
        const ushort_t* __restrict__ Bpk, const float* __restrict__ hb,
        const float* __restrict__ hbn_p, ushort_t* __restrict__ htout, int n) {
    constexpr int RB = 128;
    __shared__ __align__(16) unsigned char As[64 * RB];
    int tid = threadIdx.x, wv = tid >> 6, lane = tid & 63;
    int rowBase = blockIdx.x * 64;
#pragma unroll
    for (int it = 0; it < 8; ++it) {
        int row = wv * 16 + it * 2 + (lane >> 5), rg = rowBase + row;
        int cl = lane & 31;
        unsigned pk = 0;
        if (rg < n) pk = *(const unsigned*)(h + (size_t)rg * 64 + cl * 2);
        unsigned byte = (unsigned)(row * RB + cl * 4) ^ ((row & 7) << 4);
        *(unsigned*)(As + byte) = pk;
    }
    int hi = lane >> 4, c = lane & 15;
    short8 bf[2][4];
#pragma unroll
    for (int ks = 0; ks < 2; ++ks)
#pragma unroll
        for (int nf = 0; nf < 4; ++nf)
            bf[ks][nf] = *(const short8*)(Bpk + (((size_t)(ks * 4 + hi) * 4 + nf) * 16 + c) * 8);
    floatx4 acc[4];
#pragma unroll
    for (int nf = 0; nf < 4; ++nf)
#pragma unroll
        for (int r = 0; r < 4; ++r) acc[nf][r] = 0.f;
    int arow = wv * 16 + c;
#pragma unroll
    for (int ks = 0; ks < 2; ++ks) {
        unsigned byte = (unsigned)(arow * RB + ks * 64 + hi * 16) ^ ((arow & 7) << 4);
        short8 af = *(const short8*)(As + byte);
#pragma unroll
        for (int nf = 0; nf < 4; ++nf)
            acc[nf] = __builtin_amdgcn_mfma_f32_16x16x32_bf16(af, bf[ks][nf], acc[nf], 0, 0, 0);
    }
    float hbn = hbn_p[0];
#pragma unroll
    for (int r = 0; r < 4; ++r) {
        int row = wv * 16 + hi * 4 + r, rg = rowBase + row;
        float pn = (rg < n) ? nrm_in[rg] : 1e-15f;
        float outv[4];
        epi_row(acc, r, pn, hbn, hb, c, outv);
        if (rg < n) {
#pragma unroll
            for (int nf = 0; nf < 4; ++nf)
                htout[(size_t)rg * 64 + nf * 16 + c] = f2bf(outv[nf]);
        }
    }
}

// CSR aggregation (bf16 gathers, 8-deep ILP, packed 4B edges) + HypAct
template <bool TANGENT_OUT>
__global__ __launch_bounds__(256) void k_agg_act(
        const ushort_t* __restrict__ ht, const int* __restrict__ off,
        const unsigned* __restrict__ pe, ushort_t* __restrict__ hout,
        float* __restrict__ nrm_out, int n) {
    int wv = threadIdx.x >> 6, lane = threadIdx.x & 63;
    int node = blockIdx.x * 4 + wv;
    if (node >= n) return;
    node = __builtin_amdgcn_readfirstlane(node);
    int beg = off[node], end = off[node + 1];
    float ac[8];
#pragma unroll
    for (int u = 0; u < 8; ++u) ac[u] = 0.f;
    int e = beg;
    for (; e + 7 < end; e += 8) {
        unsigned p[8];
#pragma unroll
        for (int u = 0; u < 8; ++u) p[u] = pe[e + u];
#pragma unroll
        for (int u = 0; u < 8; ++u)
            ac[u] = fmaf(pe_adj(p[u]),
                         bf2f(ht[(size_t)(p[u] >> 15) * 64 + lane]), ac[u]);
    }
    for (; e < end; ++e) {
        unsigned p = pe[e];
        ac[0] = fmaf(pe_adj(p), bf2f(ht[(size_t)(p >> 15) * 64 + lane]), ac[0]);
    }
    float acc = ((ac[0] + ac[1]) + (ac[2] + ac[3])) +
                ((ac[4] + ac[5]) + (ac[6] + ac[7]));
    float un = fmaxf(sqrtf(wave_sum(acc * acc)), 1e-15f);
    float thu = fast_tanh(un);
    float pf = thu / un, pn = thu;
    if (thu > 0.996f) { pf = 0.996f / un; pn = 0.996f; }
    float pnc = fmaxf(pn, 1e-15f);
    float t = artanh_clip(pnc) / pnc * pf * acc;   // logmap0(proj(expmap0(acc)))
    t = fmaxf(t, 0.f);                              // relu
    float tn = fmaxf(sqrtf(wave_sum(t * t)), 1e-15f);
    if (TANGENT_OUT) {
        float o = (tn > ATH996) ? (ATH996 / tn) * t : t;
        hout[(size_t)node * 64 + lane] = f2bf(o);
    } else {
        float tht = fast_tanh(tn);
        float rf = tht / tn, rn = tht;
        if (tht > 0.996f) { rf = 0.996f / tn; rn = 0.996f; }
        hout[(size_t)node * 64 + lane] = f2bf(rf * t);
        if (lane == 0) nrm_out[node] = fmaxf(rn, 1e-15f);
    }
}

// MFMA head: z = relu(t@W4.T+b4); out = log_softmax(z@W5.T+b5)
__global__ __launch_bounds__(256) void k_head(
        const ushort_t* __restrict__ t_in, const ushort_t* __restrict__ Bpk4,
        const float* __restrict__ b4, const ushort_t* __restrict__ Bpk5,
        const float* __restrict__ b5, float* __restrict__ out, int n) {
    constexpr int RB = 128;
    __shared__ __align__(16) unsigned char As[64 * RB];
    __shared__ __align__(16) unsigned char Zs[4][16 * 80];  // 80B rows: 2-way max
    int tid = threadIdx.x, wv = tid >> 6, lane = tid & 63;
    int rowBase = blockIdx.x * 64;
#pragma unroll
    for (int it = 0; it < 8; ++it) {
        int row = wv * 16 + it * 2 + (lane >> 5), rg = rowBase + row;
        int cl = lane & 31;
        unsigned pk = 0;
        if (rg < n) pk = *(const unsigned*)(t_in + (size_t)rg * 64 + cl * 2);
        unsigned byte = (unsigned)(row * RB + cl * 4) ^ ((row & 7) << 4);
        *(unsigned*)(As + byte) = pk;
    }
    int hi = lane >> 4, c = lane & 15;
    short8 bf4[2][2];
#pragma unroll
    for (int ks = 0; ks < 2; ++ks)
#pragma unroll
        for (int nf = 0; nf < 2; ++nf)
            bf4[ks][nf] = *(const short8*)(Bpk4 + (((size_t)(ks * 4 + hi) * 2 + nf) * 16 + c) * 8);
    floatx4 acc[2];
#pragma unroll
    for (int nf = 0; nf < 2; ++nf)
#pragma unroll
        for (int r = 0; r < 4; ++r) acc[nf][r] = 0.f;
    int arow = wv * 16 + c;
#pragma unroll
    for (int ks = 0; ks < 2; ++ks) {
        unsigned byte = (unsigned)(arow * RB + ks * 64 + hi * 16) ^ ((arow & 7) << 4);
        short8 af = *(const short8*)(As + byte);
#pragma unroll
        for (int nf = 0; nf < 2; ++nf)
            acc[nf] = __builtin_amdgcn_mfma_f32_16x16x32_bf16(af, bf4[ks][nf], acc[nf], 0, 0, 0);
    }
    float bb0 = b4[c], bb1 = b4[16 + c];
#pragma unroll
    for (int r = 0; r < 4; ++r) {
        int zr = hi * 4 + r;
        *(ushort_t*)(Zs[wv] + zr * 80 + c * 2) = f2bf(fmaxf(acc[0][r] + bb0, 0.f));
        *(ushort_t*)(Zs[wv] + zr * 80 + (16 + c) * 2) = f2bf(fmaxf(acc[1][r] + bb1, 0.f));
    }
    short8 bf5 = *(const short8*)(Bpk5 + ((size_t)(hi * 16 + c)) * 8);
    short8 zf = *(const short8*)(Zs[wv] + c * 80 + hi * 16);
    floatx4 acc5;
#pragma unroll
    for (int r = 0; r < 4; ++r) acc5[r] = 0.f;
    acc5 = __builtin_amdgcn_mfma_f32_16x16x32_bf16(zf, bf5, acc5, 0, 0, 0);
    float b5v = b5[c];
#pragma unroll
    for (int r = 0; r < 4; ++r) {
        float y = acc5[r] + b5v;
        float mx = y;
#pragma unroll
        for (int mk = 1; mk < 16; mk <<= 1) mx = fmaxf(mx, __shfl_xor(mx, mk, 64));
        float sm = __expf(y - mx);
#pragma unroll
        for (int mk = 1; mk < 16; mk <<= 1) sm += __shfl_xor(sm, mk, 64);
        int rg = rowBase + wv * 16 + hi * 4 + r;
        if (rg < n) out[(size_t)rg * 16 + c] = y - mx - __logf(sm);
    }
}

extern "C" void kernel_launch(void* const* d_in, const int* in_sizes, int n_in,
                              void* d_out, int out_size, void* d_ws, size_t ws_size,
                              hipStream_t stream) {
    const float* x   = (const float*)d_in[0];
    const int*   src = (const int*)d_in[1];
    const int*   dst = (const int*)d_in[2];
    const float* adj = (const float*)d_in[3];
    const float* W1  = (const float*)d_in[4];  const float* b1 = (const float*)d_in[5];
    const float* W2  = (const float*)d_in[6];  const float* b2 = (const float*)d_in[7];
    const float* W3  = (const float*)d_in[8];  const float* b3 = (const float*)d_in[9];
    const float* W4  = (const float*)d_in[10]; const float* b4 = (const float*)d_in[11];
    const float* W5  = (const float*)d_in[12]; const float* b5 = (const float*)d_in[13];
    float* out = (float*)d_out;

    const int N = in_sizes[0] / NFEAT;
    const int E = in_sizes[1];

    // ws layout
    int* off   = (int*)d_ws;            // N+1
    int* cnt   = off + (N + 1);         // N
    int* bsums = cnt + N;               // 1024
    int* lr    = bsums + 1024;          // E
    unsigned* pe = (unsigned*)(lr + E); // E packed edges (sorted by dst)
    ushort_t* B = (ushort_t*)(pe + E);                  // ht  bf16 [N,64]
    ushort_t* D = B + (size_t)N * 64;                   // h/t bf16 [N,64]
    float* nrm  = (float*)(D + (size_t)N * 64);         // ||h|| fp32 [N]
    float* hbs  = nrm + N;              // 3*64
    float* hbns = hbs + 192;            // 3 (+1 pad)
    ushort_t* Bpk1 = (ushort_t*)(hbns + 4);             // 8192
    ushort_t* Bpk2 = Bpk1 + 8192;                       // 4096
    ushort_t* Bpk3 = Bpk2 + 4096;                       // 4096
    ushort_t* Bpk4 = Bpk3 + 4096;                       // 2048
    ushort_t* Bpk5 = Bpk4 + 2048;                       // 512

    dim3 blk(256);
    int nodeBlocks = (N + 3) / 4;
    int gemmBlocks = (N + 63) / 64;
    int edgeThBlocks = (E + 255) / 256;
    int nb = (N + SCAN_B - 1) / SCAN_B;

    // prep (weights+bias in one launch) + CSR build
    k_prep<<<75, blk, 0, stream>>>(W1, W2, W3, W4, W5, b1, b2, b3,
                                   Bpk1, Bpk2, Bpk3, Bpk4, Bpk5, hbs, hbns);
    hipMemsetAsync(cnt, 0, (size_t)N * sizeof(int), stream);
    k_rank<<<edgeThBlocks, blk, 0, stream>>>(dst, cnt, lr, E);
    k_scan1<<<nb, blk, 0, stream>>>(cnt, off, bsums, N);
    k_scan2<<<1, blk, 0, stream>>>(bsums, nb, off, N);
    k_scan3<<<(N + 255) / 256, blk, 0, stream>>>(off, bsums, N);
    k_build<<<edgeThBlocks, blk, 0, stream>>>(dst, src, adj, off, lr, pe, E);

    // layer 1
    k_gemm1<<<gemmBlocks, blk, 0, stream>>>(x, Bpk1, hbs, hbns, B, N);
    k_agg_act<false><<<nodeBlocks, blk, 0, stream>>>(B, off, pe, D, nrm, N);
    // layer 2
    k_gemm64<<<gemmBlocks, blk, 0, stream>>>(D, nrm, Bpk2, hbs + 64, hbns + 1, B, N);
    k_agg_act<false><<<nodeBlocks, blk, 0, stream>>>(B, off, pe, D, nrm, N);
    // layer 3
    k_gemm64<<<gemmBlocks, blk, 0, stream>>>(D, nrm, Bpk3, hbs + 128, hbns + 2, B, N);
    k_agg_act<true><<<nodeBlocks, blk, 0, stream>>>(B, off, pe, D, nullptr, N);

    // head (MFMA)
    k_head<<<gemmBlocks, blk, 0, stream>>>(D, Bpk4, b4, Bpk5, b5, out, N);
}